// Round 6
// baseline (1514.449 us; speedup 1.0000x reference)
//
#include <hip/hip_runtime.h>
#include <math.h>

#define MDIM 128
#define MY 10
#define GAMMA 0.8f
#define KITER 5
#define CSHIFT 13            // column chunk = 8192 cols = 2 MB of Yh (fits XCD L2)
#define CCHUNK 13            // ceil(100000 / 8192)
#define SCAN_BLK 8192        // elements per scan block (256 thr x 32)

__device__ __forceinline__ float bf2f(unsigned short h) {
    return __uint_as_float(((unsigned int)h) << 16);
}
__device__ __forceinline__ unsigned short f2bf(float f) {
    unsigned int u = __float_as_uint(f);
    u += 0x7fffu + ((u >> 16) & 1u);  // round-to-nearest-even
    return (unsigned short)(u >> 16);
}

// ---------------------------------------------------------------- transpose
// X [128][n] -> Y0 fp32 [n][128], Y0h bf16 anchor (persistent), Yh bf16 state
__global__ void k_transpose(const float* __restrict__ X, float* __restrict__ Y0,
                            unsigned short* __restrict__ Y0h,
                            unsigned short* __restrict__ Yh0, int n) {
    __shared__ float tile[32][33];
    int r0 = blockIdx.x * 32;
    int f0 = blockIdx.y * 32;
    int tx = threadIdx.x, ty = threadIdx.y;  // 32 x 8
    #pragma unroll
    for (int i = 0; i < 32; i += 8) {
        tile[ty + i][tx] = X[(size_t)(f0 + ty + i) * n + (r0 + tx)];
    }
    __syncthreads();
    #pragma unroll
    for (int i = 0; i < 32; i += 8) {
        float v = tile[tx][ty + i];
        unsigned short h = f2bf(v);
        Y0[(size_t)(r0 + ty + i) * MDIM + (f0 + tx)] = v;
        Y0h[(size_t)(r0 + ty + i) * MDIM + (f0 + tx)] = h;
        Yh0[(size_t)(r0 + ty + i) * MDIM + (f0 + tx)] = h;
    }
}

// ---------------------------------------------------------------- Gram matrix
__global__ void k_gram(const float* __restrict__ F, float* __restrict__ FF,
                       float* __restrict__ normAcc) {
    int i = blockIdx.x, j = threadIdx.x;
    float acc = 0.f;
    for (int k = 0; k < MDIM; ++k)
        acc = fmaf(F[k * MDIM + i], F[k * MDIM + j], acc);
    FF[i * MDIM + j] = acc;
    __shared__ float red[MDIM];
    red[j] = acc * acc;
    __syncthreads();
    for (int s = 64; s > 0; s >>= 1) {
        if (j < s) red[j] += red[j + s];
        __syncthreads();
    }
    if (j == 0) atomicAdd(normAcc, red[0]);
}

__global__ void k_gnorm(const float* __restrict__ FF, const float* __restrict__ normAcc,
                        float* __restrict__ G) {
    int idx = blockIdx.x * 256 + threadIdx.x;
    float s = GAMMA / (sqrtf(*normAcc) + 1e-6f);
    G[idx] = FF[idx] * s;
}

// ---------------------------------------------------------------- CSR build
// Chunk-major buckets: bucket(c, r) = c*n + r. For a fixed chunk c, all rows'
// segments are laid out row-ascending; the fused kernel sweeps chunks in its
// OUTER loop with the whole grid co-resident, so the gather working set at any
// instant is one 2 MB column chunk (L2-resident) instead of the full 25.6 MB.
__global__ void k_hist(const int* __restrict__ erow, const int* __restrict__ ecol,
                       int* __restrict__ cnt, int E, int n) {
    int e = blockIdx.x * 256 + threadIdx.x;
    if (e < E) atomicAdd(&cnt[(ecol[e] >> CSHIFT) * n + erow[e]], 1);
}

__global__ void k_scan1(const int* __restrict__ cnt, int* __restrict__ blockSums, int nC) {
    int tid = threadIdx.x;  // 256
    int base = blockIdx.x * SCAN_BLK + tid * 32;
    int s = 0;
    if (base + 31 < nC) {
        #pragma unroll
        for (int i = 0; i < 8; ++i) {
            int4 v = *(const int4*)&cnt[base + i * 4];
            s += v.x + v.y + v.z + v.w;
        }
    } else {
        for (int i = 0; i < 32; ++i)
            if (base + i < nC) s += cnt[base + i];
    }
    __shared__ int red[256];
    red[tid] = s;
    __syncthreads();
    for (int st = 128; st > 0; st >>= 1) {
        if (tid < st) red[tid] += red[tid + st];
        __syncthreads();
    }
    if (tid == 0) blockSums[blockIdx.x] = red[0];
}

__global__ void k_scan2(int* __restrict__ blockSums, int* __restrict__ rc_off,
                        int nb, int nC) {
    __shared__ int s[256];
    int tid = threadIdx.x;  // 256
    int v = (tid < nb) ? blockSums[tid] : 0;
    s[tid] = v;
    __syncthreads();
    for (int off = 1; off < 256; off <<= 1) {
        int t = (tid >= off) ? s[tid - off] : 0;
        __syncthreads();
        s[tid] += t;
        __syncthreads();
    }
    if (tid < nb) blockSums[tid] = s[tid] - v;
    if (tid == 0) rc_off[nC] = s[255];
}

__global__ void k_scan3(const int* __restrict__ cnt, const int* __restrict__ blockOff,
                        int* __restrict__ rc_off, int nC) {
    int tid = threadIdx.x;  // 256
    int base = blockIdx.x * SCAN_BLK + tid * 32;
    int v[32];
    #pragma unroll
    for (int i = 0; i < 32; ++i) v[i] = (base + i < nC) ? cnt[base + i] : 0;
    int local = 0;
    #pragma unroll
    for (int i = 0; i < 32; ++i) local += v[i];
    __shared__ int s[256];
    s[tid] = local;
    __syncthreads();
    for (int off = 1; off < 256; off <<= 1) {
        int t = (tid >= off) ? s[tid - off] : 0;
        __syncthreads();
        s[tid] += t;
        __syncthreads();
    }
    int excl = s[tid] - local + blockOff[blockIdx.x];
    #pragma unroll
    for (int i = 0; i < 32; ++i) {
        if (base + i < nC) { rc_off[base + i] = excl; excl += v[i]; }
    }
}

// Packed CSR entry {col_byte_offset, val}: one 8B scattered store per edge.
__global__ void k_scatter(const int* __restrict__ erow, const int* __restrict__ ecol,
                          const float* __restrict__ eval_, int* __restrict__ cursor,
                          int2* __restrict__ csr_cv, int E, int n) {
    int e = blockIdx.x * 256 + threadIdx.x;
    if (e < E) {
        int r = erow[e];
        int c = ecol[e];
        int pos = atomicAdd(&cursor[(c >> CSHIFT) * n + r], 1);
        csr_cv[pos] = make_int2(c << 8, __float_as_int(eval_[e]));
    }
}

// one conditional edge step: load packed entry, gather bf16 row slice, fma.
#define EDGE_STEP(eCur, eEnd, acc)                                        \
    if (eCur < eEnd) {                                                    \
        int2 p = csr_cv[eCur++];                                          \
        float v = __int_as_float(p.y);                                    \
        ushort4 h = *(const ushort4*)(yb + (size_t)(p.x + lbo));          \
        acc.x = fmaf(v, bf2f(h.x), acc.x);                                \
        acc.y = fmaf(v, bf2f(h.y), acc.y);                                \
        acc.z = fmaf(v, bf2f(h.z), acc.z);                                \
        acc.w = fmaf(v, bf2f(h.w), acc.w);                                \
    }

// ---------------------------------------------------------------- fused SpMM + dense update
// Block owns 64 rows (two 32-row tiles). OUTER loop over column chunks; all
// 1563 blocks are co-resident (16 KB LDS, <=64 VGPR -> 8 blocks/CU = 2048
// slots), so the grid sweeps chunks in phase and each 2 MB chunk of Yh stays
// L2-resident while it is being gathered. Row accumulators live in registers
// across chunks (per-row FP order = chunk-ascending storage order). Short
// per-chunk segments (~1.2 edges) are walked with 4 interleaved cursors for
// memory-level parallelism. Dense phase per tile reuses the 16 KB sSY with no
// barriers (producer lanes = consumer lanes' wave).
__global__ void __launch_bounds__(256, 8) k_fused(const unsigned short* __restrict__ Yh,
                                                  const int* __restrict__ rc_off,
                                                  const int2* __restrict__ csr_cv,
                                                  const float* __restrict__ G,
                                                  const float* __restrict__ Y0,
                                                  const unsigned short* __restrict__ Y0h,
                                                  float* __restrict__ Yout,
                                                  unsigned short* __restrict__ Yhout,
                                                  float* __restrict__ stats,
                                                  int writeH, int writeF, int n) {
    __shared__ float sSY[32 * MDIM];    // 16 KB (reused per tile + BN partials)
    int tid = threadIdx.x;
    int ty = tid >> 5;          // group 0..7
    int tx = tid & 31;          // lane-in-group, owns features tx*4..tx*4+3
    int rbase0 = blockIdx.x * 64;        // tile 0 rows: rbase0 + ty*4 ..+3
    int rbase1 = rbase0 + 32;            // tile 1 rows
    bool hasT1 = (rbase1 < n);
    const char* yb = (const char*)Yh;
    int lbo = tx * 8;           // lane byte offset within a Yh row

    float4 a0 = make_float4(0.f, 0.f, 0.f, 0.f);
    float4 a1 = a0, a2 = a0, a3 = a0;    // tile 0 accumulators (4 rows)
    float4 b0 = a0, b1 = a0, b2 = a0, b3 = a0;  // tile 1 accumulators

    // ---- gather: chunk-major sweep, register accumulation
    for (int c = 0; c < CCHUNK; ++c) {
        {
            int base = c * n + rbase0 + ty * 4;
            int4 bb = *(const int4*)&rc_off[base];
            int b4 = rc_off[base + 4];
            int e0 = bb.x, e1 = bb.y, e2 = bb.z, e3 = bb.w;
            while ((e0 < bb.y) | (e1 < bb.z) | (e2 < bb.w) | (e3 < b4)) {
                EDGE_STEP(e0, bb.y, a0)
                EDGE_STEP(e1, bb.z, a1)
                EDGE_STEP(e2, bb.w, a2)
                EDGE_STEP(e3, b4, a3)
            }
        }
        if (hasT1) {
            int base = c * n + rbase1 + ty * 4;
            int4 bb = *(const int4*)&rc_off[base];
            int b4 = rc_off[base + 4];
            int e0 = bb.x, e1 = bb.y, e2 = bb.z, e3 = bb.w;
            while ((e0 < bb.y) | (e1 < bb.z) | (e2 < bb.w) | (e3 < b4)) {
                EDGE_STEP(e0, bb.y, b0)
                EDGE_STEP(e1, bb.z, b1)
                EDGE_STEP(e2, bb.w, b2)
                EDGE_STEP(e3, b4, b3)
            }
        }
    }

    // ---- dense phase per tile: thread computes 4 rows x 4 features
    int f0 = tx * 4;
    float4 bs = make_float4(0.f, 0.f, 0.f, 0.f);
    float4 bq = make_float4(0.f, 0.f, 0.f, 0.f);

    for (int t = 0; t < 2; ++t) {
        if (t == 1 && !hasT1) break;
        // stage this tile's SY rows into LDS (same-wave produce/consume)
        *(float4*)&sSY[(ty * 4 + 0) * MDIM + f0] = (t == 0) ? a0 : b0;
        *(float4*)&sSY[(ty * 4 + 1) * MDIM + f0] = (t == 0) ? a1 : b1;
        *(float4*)&sSY[(ty * 4 + 2) * MDIM + f0] = (t == 0) ? a2 : b2;
        *(float4*)&sSY[(ty * 4 + 3) * MDIM + f0] = (t == 0) ? a3 : b3;

        size_t r0 = (size_t)(t == 0 ? rbase0 : rbase1) + ty * 4;
        float4 acc[4];
        #pragma unroll
        for (int i = 0; i < 4; ++i) acc[i] = make_float4(0.f, 0.f, 0.f, 0.f);
        for (int j = 0; j < MDIM; j += 4) {
            float4 g0 = *(const float4*)&G[(j + 0) * MDIM + f0];
            float4 g1 = *(const float4*)&G[(j + 1) * MDIM + f0];
            float4 g2 = *(const float4*)&G[(j + 2) * MDIM + f0];
            float4 g3 = *(const float4*)&G[(j + 3) * MDIM + f0];
            #pragma unroll
            for (int i = 0; i < 4; ++i) {
                float4 sr = *(const float4*)&sSY[(ty * 4 + i) * MDIM + j];
                acc[i].x = fmaf(sr.x, g0.x, acc[i].x);
                acc[i].y = fmaf(sr.x, g0.y, acc[i].y);
                acc[i].z = fmaf(sr.x, g0.z, acc[i].z);
                acc[i].w = fmaf(sr.x, g0.w, acc[i].w);
                acc[i].x = fmaf(sr.y, g1.x, acc[i].x);
                acc[i].y = fmaf(sr.y, g1.y, acc[i].y);
                acc[i].z = fmaf(sr.y, g1.z, acc[i].z);
                acc[i].w = fmaf(sr.y, g1.w, acc[i].w);
                acc[i].x = fmaf(sr.z, g2.x, acc[i].x);
                acc[i].y = fmaf(sr.z, g2.y, acc[i].y);
                acc[i].z = fmaf(sr.z, g2.z, acc[i].z);
                acc[i].w = fmaf(sr.z, g2.w, acc[i].w);
                acc[i].x = fmaf(sr.w, g3.x, acc[i].x);
                acc[i].y = fmaf(sr.w, g3.y, acc[i].y);
                acc[i].z = fmaf(sr.w, g3.z, acc[i].z);
                acc[i].w = fmaf(sr.w, g3.w, acc[i].w);
            }
        }

        #pragma unroll
        for (int i = 0; i < 4; ++i) {
            float4 y0;
            if (writeF) {
                y0 = *(const float4*)&Y0[(r0 + i) * MDIM + f0];
            } else {
                ushort4 t4 = *(const ushort4*)&Y0h[(r0 + i) * MDIM + f0];
                y0.x = bf2f(t4.x);
                y0.y = bf2f(t4.y);
                y0.z = bf2f(t4.z);
                y0.w = bf2f(t4.w);
            }
            float4 o;
            o.x = acc[i].x + y0.x;
            o.y = acc[i].y + y0.y;
            o.z = acc[i].z + y0.z;
            o.w = acc[i].w + y0.w;
            if (writeF) {
                *(float4*)&Yout[(r0 + i) * MDIM + f0] = o;
                bs.x += o.x; bs.y += o.y; bs.z += o.z; bs.w += o.w;
                bq.x = fmaf(o.x, o.x, bq.x);
                bq.y = fmaf(o.y, o.y, bq.y);
                bq.z = fmaf(o.z, o.z, bq.z);
                bq.w = fmaf(o.w, o.w, bq.w);
            }
            if (writeH) {
                ushort4 h;
                h.x = f2bf(o.x);
                h.y = f2bf(o.y);
                h.z = f2bf(o.z);
                h.w = f2bf(o.w);
                *(ushort4*)&Yhout[(r0 + i) * MDIM + f0] = h;
            }
        }
    }

    // ---- fused BN partial stats (final iteration only)
    if (writeF) {
        __syncthreads();  // everyone done with sSY tiles
        *(float4*)&sSY[ty * MDIM + f0] = bs;
        *(float4*)&sSY[8 * MDIM + ty * MDIM + f0] = bq;
        __syncthreads();
        if (tid < MDIM) {
            float a = 0.f, b = 0.f;
            #pragma unroll
            for (int t = 0; t < 8; ++t) {
                a += sSY[t * MDIM + tid];
                b += sSY[8 * MDIM + t * MDIM + tid];
            }
            atomicAdd(&stats[tid], a);
            atomicAdd(&stats[MDIM + tid], b);
        }
    }
}

// ---------------------------------------------------------------- BN finalize
__global__ void k_finalize(const float* __restrict__ stats, const float* __restrict__ B,
                           const float* __restrict__ bnw, const float* __restrict__ bnb,
                           float* __restrict__ Bs, float* __restrict__ cvec, int n) {
    int f = threadIdx.x;
    float inv_n = 1.f / (float)n;
    float mu = stats[f] * inv_n;
    float var = stats[MDIM + f] * inv_n - mu * mu;
    float rs = rsqrtf(var + 1e-5f);
    float sw = rs * bnw[f];
    float cv = bnb[f] - mu * sw;
    __shared__ float red[MDIM];
    for (int o = 0; o < MY; ++o) {
        float b = B[o * MDIM + f];
        Bs[o * MDIM + f] = b * sw;
        red[f] = b * cv;
        __syncthreads();
        for (int s = 64; s > 0; s >>= 1) {
            if (f < s) red[f] += red[f + s];
            __syncthreads();
        }
        if (f == 0) cvec[o] = red[0];
        __syncthreads();
    }
}

// ---------------------------------------------------------------- projection
__global__ void __launch_bounds__(256) k_project(const float* __restrict__ Y,
                                                 const float* __restrict__ Bs,
                                                 const float* __restrict__ cvec,
                                                 float* __restrict__ out, int n) {
    __shared__ float yt[16 * 129];
    __shared__ float sB[MY * 129];
    __shared__ float sc[MY];
    int tid = threadIdx.x;
    size_t rbase = (size_t)blockIdx.x * 16;
    for (int idx = tid; idx < 16 * MDIM; idx += 256) {
        int r = idx >> 7, f = idx & 127;
        yt[r * 129 + f] = Y[(rbase + r) * MDIM + f];
    }
    for (int idx = tid; idx < MY * MDIM; idx += 256) {
        int o = idx >> 7, f = idx & 127;
        sB[o * 129 + f] = Bs[idx];
    }
    if (tid < MY) sc[tid] = cvec[tid];
    __syncthreads();
    if (tid < 16 * MY) {
        int r = tid / MY, o = tid % MY;
        float acc = sc[o];
        for (int f = 0; f < MDIM; ++f)
            acc = fmaf(yt[r * 129 + f], sB[o * 129 + f], acc);
        out[(rbase + r) * MY + o] = acc;
    }
}

// ---------------------------------------------------------------- launch
extern "C" void kernel_launch(void* const* d_in, const int* in_sizes, int n_in,
                              void* d_out, int out_size, void* d_ws, size_t ws_size,
                              hipStream_t stream) {
    const float* X    = (const float*)d_in[0];
    const float* F    = (const float*)d_in[1];
    const float* B    = (const float*)d_in[2];
    const float* bnw  = (const float*)d_in[3];
    const float* bnb  = (const float*)d_in[4];
    const float* ev   = (const float*)d_in[5];
    const int*   erow = (const int*)d_in[6];
    const int*   ecol = (const int*)d_in[7];
    float* out = (float*)d_out;
    const int n = in_sizes[0] / MDIM;  // 100000
    const int E = in_sizes[5];         // 1600000
    const int nC = n * CCHUNK;

    char* w = (char*)d_ws;
    size_t off = 0;
    auto carve = [&](size_t bytes) -> void* {
        void* p = w + off;
        off += (bytes + 255) & ~(size_t)255;
        return p;
    };
    float*          Y0    = (float*)carve((size_t)n * MDIM * 4);
    float*          Ycur  = (float*)carve((size_t)n * MDIM * 4);
    unsigned short* Y0h   = (unsigned short*)carve((size_t)n * MDIM * 2);  // bf16 anchor
    unsigned short* Yh_a  = (unsigned short*)carve((size_t)n * MDIM * 2);  // bf16 state ping
    unsigned short* Yh_b  = (unsigned short*)carve((size_t)n * MDIM * 2);  // bf16 state pong
    float* FF        = (float*)carve(MDIM * MDIM * 4);
    float* G         = (float*)carve(MDIM * MDIM * 4);
    int2*  csr_cv    = (int2*)carve((size_t)E * 8);
    int*   rc_off    = (int*)carve((size_t)(nC + 1) * 4);
    int*   cursor    = (int*)carve((size_t)nC * 4);
    int*   cnt       = (int*)carve((size_t)nC * 4);
    int*   blockSums = (int*)carve(1024 * 4);
    float* normAcc   = (float*)carve(4);
    float* stats     = (float*)carve(2 * MDIM * 4);
    float* Bs        = (float*)carve(MY * MDIM * 4);
    float* cvec      = (float*)carve(MY * 4);
    (void)ws_size;

    hipMemsetAsync(cnt, 0, (size_t)nC * 4, stream);
    hipMemsetAsync(normAcc, 0, 4, stream);
    hipMemsetAsync(stats, 0, 2 * MDIM * 4, stream);

    k_transpose<<<dim3(n / 32, MDIM / 32), dim3(32, 8), 0, stream>>>(X, Y0, Y0h, Yh_a, n);
    k_gram<<<MDIM, MDIM, 0, stream>>>(F, FF, normAcc);
    k_gnorm<<<MDIM * MDIM / 256, 256, 0, stream>>>(FF, normAcc, G);

    const int nb = (nC + SCAN_BLK - 1) / SCAN_BLK;   // 159 <= 256
    k_hist<<<(E + 255) / 256, 256, 0, stream>>>(erow, ecol, cnt, E, n);
    k_scan1<<<nb, 256, 0, stream>>>(cnt, blockSums, nC);
    k_scan2<<<1, 256, 0, stream>>>(blockSums, rc_off, nb, nC);
    k_scan3<<<nb, 256, 0, stream>>>(cnt, blockSums, rc_off, nC);
    hipMemcpyAsync(cursor, rc_off, (size_t)nC * 4, hipMemcpyDeviceToDevice, stream);
    k_scatter<<<(E + 255) / 256, 256, 0, stream>>>(erow, ecol, ev, cursor, csr_cv, E, n);

    const int nblk = (n + 63) / 64;   // 1563 blocks <= 2048 co-resident slots
    for (int k = 0; k < KITER; ++k) {
        const unsigned short* hin = (k & 1) ? Yh_b : Yh_a;
        unsigned short*       hout = (k & 1) ? Yh_a : Yh_b;
        int writeH = (k < KITER - 1) ? 1 : 0;
        int writeF = (k == KITER - 1) ? 1 : 0;
        k_fused<<<nblk, 256, 0, stream>>>(hin, rc_off, csr_cv, G, Y0, Y0h, Ycur, hout,
                                          stats, writeH, writeF, n);
    }

    k_finalize<<<1, MDIM, 0, stream>>>(stats, B, bnw, bnb, Bs, cvec, n);
    k_project<<<n / 16, 256, 0, stream>>>(Ycur, Bs, cvec, out, n);
}

// Round 7
// 1331.042 us; speedup vs baseline: 1.1378x; 1.1378x over previous
//
#include <hip/hip_runtime.h>
#include <math.h>

#define MDIM 128
#define MY 10
#define GAMMA 0.8f
#define KITER 5
#define CSHIFT 13            // column chunk = 8192 cols = 2 MB of Yh (fits XCD L2)
#define CCHUNK 13            // ceil(100000 / 8192)
#define SCAN_BLK 8192        // elements per scan block (256 thr x 32)

__device__ __forceinline__ float bf2f(unsigned short h) {
    return __uint_as_float(((unsigned int)h) << 16);
}
__device__ __forceinline__ unsigned short f2bf(float f) {
    unsigned int u = __float_as_uint(f);
    u += 0x7fffu + ((u >> 16) & 1u);  // round-to-nearest-even
    return (unsigned short)(u >> 16);
}

// ---------------------------------------------------------------- transpose
// X [128][n] -> Y0 fp32 [n][128], Y0h bf16 anchor (persistent), Yh bf16 state
__global__ void k_transpose(const float* __restrict__ X, float* __restrict__ Y0,
                            unsigned short* __restrict__ Y0h,
                            unsigned short* __restrict__ Yh0, int n) {
    __shared__ float tile[32][33];
    int r0 = blockIdx.x * 32;
    int f0 = blockIdx.y * 32;
    int tx = threadIdx.x, ty = threadIdx.y;  // 32 x 8
    #pragma unroll
    for (int i = 0; i < 32; i += 8) {
        tile[ty + i][tx] = X[(size_t)(f0 + ty + i) * n + (r0 + tx)];
    }
    __syncthreads();
    #pragma unroll
    for (int i = 0; i < 32; i += 8) {
        float v = tile[tx][ty + i];
        unsigned short h = f2bf(v);
        Y0[(size_t)(r0 + ty + i) * MDIM + (f0 + tx)] = v;
        Y0h[(size_t)(r0 + ty + i) * MDIM + (f0 + tx)] = h;
        Yh0[(size_t)(r0 + ty + i) * MDIM + (f0 + tx)] = h;
    }
}

// ---------------------------------------------------------------- Gram matrix
__global__ void k_gram(const float* __restrict__ F, float* __restrict__ FF,
                       float* __restrict__ normAcc) {
    int i = blockIdx.x, j = threadIdx.x;
    float acc = 0.f;
    for (int k = 0; k < MDIM; ++k)
        acc = fmaf(F[k * MDIM + i], F[k * MDIM + j], acc);
    FF[i * MDIM + j] = acc;
    __shared__ float red[MDIM];
    red[j] = acc * acc;
    __syncthreads();
    for (int s = 64; s > 0; s >>= 1) {
        if (j < s) red[j] += red[j + s];
        __syncthreads();
    }
    if (j == 0) atomicAdd(normAcc, red[0]);
}

__global__ void k_gnorm(const float* __restrict__ FF, const float* __restrict__ normAcc,
                        float* __restrict__ G) {
    int idx = blockIdx.x * 256 + threadIdx.x;
    float s = GAMMA / (sqrtf(*normAcc) + 1e-6f);
    G[idx] = FF[idx] * s;
}

// ---------------------------------------------------------------- CSR build
// Chunk-major buckets: bucket(c, r) = c*n + r. The fused kernel sweeps chunks
// in its OUTER loop with nearly the whole grid co-resident, so the gather
// working set at any instant is ~one 2 MB column chunk (L2-resident) instead
// of the full 25.6 MB Yh.
__global__ void k_hist(const int* __restrict__ erow, const int* __restrict__ ecol,
                       int* __restrict__ cnt, int E, int n) {
    int e = blockIdx.x * 256 + threadIdx.x;
    if (e < E) atomicAdd(&cnt[(ecol[e] >> CSHIFT) * n + erow[e]], 1);
}

__global__ void k_scan1(const int* __restrict__ cnt, int* __restrict__ blockSums, int nC) {
    int tid = threadIdx.x;  // 256
    int base = blockIdx.x * SCAN_BLK + tid * 32;
    int s = 0;
    if (base + 31 < nC) {
        #pragma unroll
        for (int i = 0; i < 8; ++i) {
            int4 v = *(const int4*)&cnt[base + i * 4];
            s += v.x + v.y + v.z + v.w;
        }
    } else {
        for (int i = 0; i < 32; ++i)
            if (base + i < nC) s += cnt[base + i];
    }
    __shared__ int red[256];
    red[tid] = s;
    __syncthreads();
    for (int st = 128; st > 0; st >>= 1) {
        if (tid < st) red[tid] += red[tid + st];
        __syncthreads();
    }
    if (tid == 0) blockSums[blockIdx.x] = red[0];
}

__global__ void k_scan2(int* __restrict__ blockSums, int* __restrict__ rc_off,
                        int nb, int nC) {
    __shared__ int s[256];
    int tid = threadIdx.x;  // 256
    int v = (tid < nb) ? blockSums[tid] : 0;
    s[tid] = v;
    __syncthreads();
    for (int off = 1; off < 256; off <<= 1) {
        int t = (tid >= off) ? s[tid - off] : 0;
        __syncthreads();
        s[tid] += t;
        __syncthreads();
    }
    if (tid < nb) blockSums[tid] = s[tid] - v;
    if (tid == 0) rc_off[nC] = s[255];
}

__global__ void k_scan3(const int* __restrict__ cnt, const int* __restrict__ blockOff,
                        int* __restrict__ rc_off, int nC) {
    int tid = threadIdx.x;  // 256
    int base = blockIdx.x * SCAN_BLK + tid * 32;
    int v[32];
    #pragma unroll
    for (int i = 0; i < 32; ++i) v[i] = (base + i < nC) ? cnt[base + i] : 0;
    int local = 0;
    #pragma unroll
    for (int i = 0; i < 32; ++i) local += v[i];
    __shared__ int s[256];
    s[tid] = local;
    __syncthreads();
    for (int off = 1; off < 256; off <<= 1) {
        int t = (tid >= off) ? s[tid - off] : 0;
        __syncthreads();
        s[tid] += t;
        __syncthreads();
    }
    int excl = s[tid] - local + blockOff[blockIdx.x];
    #pragma unroll
    for (int i = 0; i < 32; ++i) {
        if (base + i < nC) { rc_off[base + i] = excl; excl += v[i]; }
    }
}

// Packed CSR entry {col_byte_offset, val}: one 8B scattered store per edge.
__global__ void k_scatter(const int* __restrict__ erow, const int* __restrict__ ecol,
                          const float* __restrict__ eval_, int* __restrict__ cursor,
                          int2* __restrict__ csr_cv, int E, int n) {
    int e = blockIdx.x * 256 + threadIdx.x;
    if (e < E) {
        int r = erow[e];
        int c = ecol[e];
        int pos = atomicAdd(&cursor[(c >> CSHIFT) * n + r], 1);
        csr_cv[pos] = make_int2(c << 8, __float_as_int(eval_[e]));
    }
}

// one conditional edge step: load packed entry, gather bf16 row slice, fma.
#define EDGE_STEP(eCur, eEnd, acc)                                        \
    if (eCur < eEnd) {                                                    \
        int2 p = csr_cv[eCur++];                                          \
        float v = __int_as_float(p.y);                                    \
        ushort4 h = *(const ushort4*)(yb + (size_t)(p.x + lbo));          \
        acc.x = fmaf(v, bf2f(h.x), acc.x);                                \
        acc.y = fmaf(v, bf2f(h.y), acc.y);                                \
        acc.z = fmaf(v, bf2f(h.z), acc.z);                                \
        acc.w = fmaf(v, bf2f(h.w), acc.w);                                \
    }

// ---------------------------------------------------------------- fused SpMM + dense update
// Block owns 32 rows (THIN: 4 float4 accumulators = 16 VGPR, no spill, true
// 8 blocks/CU). OUTER loop over column chunks: ~2048 of 3125 blocks are
// co-resident at a time and sweep chunks in phase, keeping each XCD's
// instantaneous Yh gather working set ~2 MB (L2-fit). Row accumulators live
// in registers across chunks (per-row FP order = chunk-ascending storage
// order, matching the CSR layout). Short per-chunk segments (~1.2 edges) are
// walked with 4 interleaved cursors (contiguous in the chunk-major CSR) for
// memory-level parallelism. Dense phase reuses the 16 KB sSY barrier-free
// (producer lanes = consumer lanes' wave).
__global__ void __launch_bounds__(256, 8) k_fused(const unsigned short* __restrict__ Yh,
                                                  const int* __restrict__ rc_off,
                                                  const int2* __restrict__ csr_cv,
                                                  const float* __restrict__ G,
                                                  const float* __restrict__ Y0,
                                                  const unsigned short* __restrict__ Y0h,
                                                  float* __restrict__ Yout,
                                                  unsigned short* __restrict__ Yhout,
                                                  float* __restrict__ stats,
                                                  int writeH, int writeF, int n) {
    __shared__ float sSY[32 * MDIM];    // 16 KB (reused for BN partials at the end)
    int tid = threadIdx.x;
    int ty = tid >> 5;          // group 0..7
    int tx = tid & 31;          // lane-in-group, owns features tx*4..tx*4+3
    int rbase = blockIdx.x * 32;
    const char* yb = (const char*)Yh;
    int lbo = tx * 8;           // lane byte offset within a Yh row

    float4 a0 = make_float4(0.f, 0.f, 0.f, 0.f);
    float4 a1 = a0, a2 = a0, a3 = a0;    // 4 row accumulators

    // ---- gather: chunk-major sweep, register accumulation
    for (int c = 0; c < CCHUNK; ++c) {
        int base = c * n + rbase + ty * 4;
        int4 bb = *(const int4*)&rc_off[base];
        int b4 = rc_off[base + 4];
        int e0 = bb.x, e1 = bb.y, e2 = bb.z, e3 = bb.w;
        while ((e0 < bb.y) | (e1 < bb.z) | (e2 < bb.w) | (e3 < b4)) {
            EDGE_STEP(e0, bb.y, a0)
            EDGE_STEP(e1, bb.z, a1)
            EDGE_STEP(e2, bb.w, a2)
            EDGE_STEP(e3, b4, a3)
        }
    }
    // dense phase reads these rows only from the same wave64 ->
    // intra-wave ordering suffices, no block barrier needed.
    int f0 = tx * 4;
    *(float4*)&sSY[(ty * 4 + 0) * MDIM + f0] = a0;
    *(float4*)&sSY[(ty * 4 + 1) * MDIM + f0] = a1;
    *(float4*)&sSY[(ty * 4 + 2) * MDIM + f0] = a2;
    *(float4*)&sSY[(ty * 4 + 3) * MDIM + f0] = a3;

    // ---- dense phase: thread computes 4 rows x 4 features, G from L1/L2
    size_t r0 = (size_t)rbase + ty * 4;
    float4 acc[4];
    #pragma unroll
    for (int i = 0; i < 4; ++i) acc[i] = make_float4(0.f, 0.f, 0.f, 0.f);

    for (int j = 0; j < MDIM; j += 4) {
        float4 g0 = *(const float4*)&G[(j + 0) * MDIM + f0];
        float4 g1 = *(const float4*)&G[(j + 1) * MDIM + f0];
        float4 g2 = *(const float4*)&G[(j + 2) * MDIM + f0];
        float4 g3 = *(const float4*)&G[(j + 3) * MDIM + f0];
        #pragma unroll
        for (int i = 0; i < 4; ++i) {
            float4 sr = *(const float4*)&sSY[(ty * 4 + i) * MDIM + j];
            acc[i].x = fmaf(sr.x, g0.x, acc[i].x);
            acc[i].y = fmaf(sr.x, g0.y, acc[i].y);
            acc[i].z = fmaf(sr.x, g0.z, acc[i].z);
            acc[i].w = fmaf(sr.x, g0.w, acc[i].w);
            acc[i].x = fmaf(sr.y, g1.x, acc[i].x);
            acc[i].y = fmaf(sr.y, g1.y, acc[i].y);
            acc[i].z = fmaf(sr.y, g1.z, acc[i].z);
            acc[i].w = fmaf(sr.y, g1.w, acc[i].w);
            acc[i].x = fmaf(sr.z, g2.x, acc[i].x);
            acc[i].y = fmaf(sr.z, g2.y, acc[i].y);
            acc[i].z = fmaf(sr.z, g2.z, acc[i].z);
            acc[i].w = fmaf(sr.z, g2.w, acc[i].w);
            acc[i].x = fmaf(sr.w, g3.x, acc[i].x);
            acc[i].y = fmaf(sr.w, g3.y, acc[i].y);
            acc[i].z = fmaf(sr.w, g3.z, acc[i].z);
            acc[i].w = fmaf(sr.w, g3.w, acc[i].w);
        }
    }

    float4 bs = make_float4(0.f, 0.f, 0.f, 0.f);
    float4 bq = make_float4(0.f, 0.f, 0.f, 0.f);
    #pragma unroll
    for (int i = 0; i < 4; ++i) {
        float4 y0;
        if (writeF) {
            y0 = *(const float4*)&Y0[(r0 + i) * MDIM + f0];
        } else {
            ushort4 t4 = *(const ushort4*)&Y0h[(r0 + i) * MDIM + f0];
            y0.x = bf2f(t4.x);
            y0.y = bf2f(t4.y);
            y0.z = bf2f(t4.z);
            y0.w = bf2f(t4.w);
        }
        float4 o;
        o.x = acc[i].x + y0.x;
        o.y = acc[i].y + y0.y;
        o.z = acc[i].z + y0.z;
        o.w = acc[i].w + y0.w;
        if (writeF) {
            *(float4*)&Yout[(r0 + i) * MDIM + f0] = o;
            bs.x += o.x; bs.y += o.y; bs.z += o.z; bs.w += o.w;
            bq.x = fmaf(o.x, o.x, bq.x);
            bq.y = fmaf(o.y, o.y, bq.y);
            bq.z = fmaf(o.z, o.z, bq.z);
            bq.w = fmaf(o.w, o.w, bq.w);
        }
        if (writeH) {
            ushort4 h;
            h.x = f2bf(o.x);
            h.y = f2bf(o.y);
            h.z = f2bf(o.z);
            h.w = f2bf(o.w);
            *(ushort4*)&Yhout[(r0 + i) * MDIM + f0] = h;
        }
    }

    // ---- fused BN partial stats (final iteration only)
    if (writeF) {
        __syncthreads();  // everyone done reading sSY
        *(float4*)&sSY[ty * MDIM + f0] = bs;
        *(float4*)&sSY[8 * MDIM + ty * MDIM + f0] = bq;
        __syncthreads();
        if (tid < MDIM) {
            float a = 0.f, b = 0.f;
            #pragma unroll
            for (int t = 0; t < 8; ++t) {
                a += sSY[t * MDIM + tid];
                b += sSY[8 * MDIM + t * MDIM + tid];
            }
            atomicAdd(&stats[tid], a);
            atomicAdd(&stats[MDIM + tid], b);
        }
    }
}

// ---------------------------------------------------------------- BN finalize
__global__ void k_finalize(const float* __restrict__ stats, const float* __restrict__ B,
                           const float* __restrict__ bnw, const float* __restrict__ bnb,
                           float* __restrict__ Bs, float* __restrict__ cvec, int n) {
    int f = threadIdx.x;
    float inv_n = 1.f / (float)n;
    float mu = stats[f] * inv_n;
    float var = stats[MDIM + f] * inv_n - mu * mu;
    float rs = rsqrtf(var + 1e-5f);
    float sw = rs * bnw[f];
    float cv = bnb[f] - mu * sw;
    __shared__ float red[MDIM];
    for (int o = 0; o < MY; ++o) {
        float b = B[o * MDIM + f];
        Bs[o * MDIM + f] = b * sw;
        red[f] = b * cv;
        __syncthreads();
        for (int s = 64; s > 0; s >>= 1) {
            if (f < s) red[f] += red[f + s];
            __syncthreads();
        }
        if (f == 0) cvec[o] = red[0];
        __syncthreads();
    }
}

// ---------------------------------------------------------------- projection
__global__ void __launch_bounds__(256) k_project(const float* __restrict__ Y,
                                                 const float* __restrict__ Bs,
                                                 const float* __restrict__ cvec,
                                                 float* __restrict__ out, int n) {
    __shared__ float yt[16 * 129];
    __shared__ float sB[MY * 129];
    __shared__ float sc[MY];
    int tid = threadIdx.x;
    size_t rbase = (size_t)blockIdx.x * 16;
    for (int idx = tid; idx < 16 * MDIM; idx += 256) {
        int r = idx >> 7, f = idx & 127;
        yt[r * 129 + f] = Y[(rbase + r) * MDIM + f];
    }
    for (int idx = tid; idx < MY * MDIM; idx += 256) {
        int o = idx >> 7, f = idx & 127;
        sB[o * 129 + f] = Bs[idx];
    }
    if (tid < MY) sc[tid] = cvec[tid];
    __syncthreads();
    if (tid < 16 * MY) {
        int r = tid / MY, o = tid % MY;
        float acc = sc[o];
        for (int f = 0; f < MDIM; ++f)
            acc = fmaf(yt[r * 129 + f], sB[o * 129 + f], acc);
        out[(rbase + r) * MY + o] = acc;
    }
}

// ---------------------------------------------------------------- launch
extern "C" void kernel_launch(void* const* d_in, const int* in_sizes, int n_in,
                              void* d_out, int out_size, void* d_ws, size_t ws_size,
                              hipStream_t stream) {
    const float* X    = (const float*)d_in[0];
    const float* F    = (const float*)d_in[1];
    const float* B    = (const float*)d_in[2];
    const float* bnw  = (const float*)d_in[3];
    const float* bnb  = (const float*)d_in[4];
    const float* ev   = (const float*)d_in[5];
    const int*   erow = (const int*)d_in[6];
    const int*   ecol = (const int*)d_in[7];
    float* out = (float*)d_out;
    const int n = in_sizes[0] / MDIM;  // 100000
    const int E = in_sizes[5];         // 1600000
    const int nC = n * CCHUNK;

    char* w = (char*)d_ws;
    size_t off = 0;
    auto carve = [&](size_t bytes) -> void* {
        void* p = w + off;
        off += (bytes + 255) & ~(size_t)255;
        return p;
    };
    float*          Y0    = (float*)carve((size_t)n * MDIM * 4);
    float*          Ycur  = (float*)carve((size_t)n * MDIM * 4);
    unsigned short* Y0h   = (unsigned short*)carve((size_t)n * MDIM * 2);  // bf16 anchor
    unsigned short* Yh_a  = (unsigned short*)carve((size_t)n * MDIM * 2);  // bf16 state ping
    unsigned short* Yh_b  = (unsigned short*)carve((size_t)n * MDIM * 2);  // bf16 state pong
    float* FF        = (float*)carve(MDIM * MDIM * 4);
    float* G         = (float*)carve(MDIM * MDIM * 4);
    int2*  csr_cv    = (int2*)carve((size_t)E * 8);
    int*   rc_off    = (int*)carve((size_t)(nC + 1) * 4);
    int*   cursor    = (int*)carve((size_t)nC * 4);
    int*   cnt       = (int*)carve((size_t)nC * 4);
    int*   blockSums = (int*)carve(1024 * 4);
    float* normAcc   = (float*)carve(4);
    float* stats     = (float*)carve(2 * MDIM * 4);
    float* Bs        = (float*)carve(MY * MDIM * 4);
    float* cvec      = (float*)carve(MY * 4);
    (void)ws_size;

    hipMemsetAsync(cnt, 0, (size_t)nC * 4, stream);
    hipMemsetAsync(normAcc, 0, 4, stream);
    hipMemsetAsync(stats, 0, 2 * MDIM * 4, stream);

    k_transpose<<<dim3(n / 32, MDIM / 32), dim3(32, 8), 0, stream>>>(X, Y0, Y0h, Yh_a, n);
    k_gram<<<MDIM, MDIM, 0, stream>>>(F, FF, normAcc);
    k_gnorm<<<MDIM * MDIM / 256, 256, 0, stream>>>(FF, normAcc, G);

    const int nb = (nC + SCAN_BLK - 1) / SCAN_BLK;   // 159 <= 256
    k_hist<<<(E + 255) / 256, 256, 0, stream>>>(erow, ecol, cnt, E, n);
    k_scan1<<<nb, 256, 0, stream>>>(cnt, blockSums, nC);
    k_scan2<<<1, 256, 0, stream>>>(blockSums, rc_off, nb, nC);
    k_scan3<<<nb, 256, 0, stream>>>(cnt, blockSums, rc_off, nC);
    hipMemcpyAsync(cursor, rc_off, (size_t)nC * 4, hipMemcpyDeviceToDevice, stream);
    k_scatter<<<(E + 255) / 256, 256, 0, stream>>>(erow, ecol, ev, cursor, csr_cv, E, n);

    const int nblk = (n + 31) / 32;   // 3125 blocks, ~2048 co-resident
    for (int k = 0; k < KITER; ++k) {
        const unsigned short* hin = (k & 1) ? Yh_b : Yh_a;
        unsigned short*       hout = (k & 1) ? Yh_a : Yh_b;
        int writeH = (k < KITER - 1) ? 1 : 0;
        int writeF = (k == KITER - 1) ? 1 : 0;
        k_fused<<<nblk, 256, 0, stream>>>(hin, rc_off, csr_cv, G, Y0, Y0h, Ycur, hout,
                                          stats, writeH, writeF, n);
    }

    k_finalize<<<1, MDIM, 0, stream>>>(stats, B, bnw, bnb, Bs, cvec, n);
    k_project<<<n / 16, 256, 0, stream>>>(Ycur, Bs, cvec, out, n);
}

// Round 8
// 1242.594 us; speedup vs baseline: 1.2188x; 1.0712x over previous
//
#include <hip/hip_runtime.h>
#include <math.h>

#define MDIM 128
#define MY 10
#define GAMMA 0.8f
#define KITER 5
#define BSHIFT 7             // 128 rows per scatter bucket
#define NBUCK(n) (((n) + 127) >> 7)

__device__ __forceinline__ float bf2f(unsigned short h) {
    return __uint_as_float(((unsigned int)h) << 16);
}
__device__ __forceinline__ unsigned short f2bf(float f) {
    unsigned int u = __float_as_uint(f);
    u += 0x7fffu + ((u >> 16) & 1u);  // round-to-nearest-even
    return (unsigned short)(u >> 16);
}

// ---------------------------------------------------------------- transpose
// X [128][n] -> Y0 fp32 [n][128], Y0h bf16 anchor (persistent), Yh bf16 state
__global__ void k_transpose(const float* __restrict__ X, float* __restrict__ Y0,
                            unsigned short* __restrict__ Y0h,
                            unsigned short* __restrict__ Yh0, int n) {
    __shared__ float tile[32][33];
    int r0 = blockIdx.x * 32;
    int f0 = blockIdx.y * 32;
    int tx = threadIdx.x, ty = threadIdx.y;  // 32 x 8
    #pragma unroll
    for (int i = 0; i < 32; i += 8) {
        tile[ty + i][tx] = X[(size_t)(f0 + ty + i) * n + (r0 + tx)];
    }
    __syncthreads();
    #pragma unroll
    for (int i = 0; i < 32; i += 8) {
        float v = tile[tx][ty + i];
        unsigned short h = f2bf(v);
        Y0[(size_t)(r0 + ty + i) * MDIM + (f0 + tx)] = v;
        Y0h[(size_t)(r0 + ty + i) * MDIM + (f0 + tx)] = h;
        Yh0[(size_t)(r0 + ty + i) * MDIM + (f0 + tx)] = h;
    }
}

// ---------------------------------------------------------------- Gram matrix
__global__ void k_gram(const float* __restrict__ F, float* __restrict__ FF,
                       float* __restrict__ normAcc) {
    int i = blockIdx.x, j = threadIdx.x;
    float acc = 0.f;
    for (int k = 0; k < MDIM; ++k)
        acc = fmaf(F[k * MDIM + i], F[k * MDIM + j], acc);
    FF[i * MDIM + j] = acc;
    __shared__ float red[MDIM];
    red[j] = acc * acc;
    __syncthreads();
    for (int s = 64; s > 0; s >>= 1) {
        if (j < s) red[j] += red[j + s];
        __syncthreads();
    }
    if (j == 0) atomicAdd(normAcc, red[0]);
}

__global__ void k_gnorm(const float* __restrict__ FF, const float* __restrict__ normAcc,
                        float* __restrict__ G) {
    int idx = blockIdx.x * 256 + threadIdx.x;
    float s = GAMMA / (sqrtf(*normAcc) + 1e-6f);
    G[idx] = FF[idx] * s;
}

// ---------------------------------------------------------------- CSR build (plain row CSR)
__global__ void k_hist(const int* __restrict__ erow, int* __restrict__ cnt, int E) {
    int e = blockIdx.x * 256 + threadIdx.x;
    if (e < E) atomicAdd(&cnt[erow[e]], 1);
}

__global__ void k_scan1(const int* __restrict__ cnt, int* __restrict__ blockSums, int n) {
    int tid = threadIdx.x;  // 256
    int base = blockIdx.x * 1024 + tid * 4;
    int s = 0;
    if (base + 3 < n) {
        int4 v = *(const int4*)&cnt[base];
        s = v.x + v.y + v.z + v.w;
    } else {
        for (int i = 0; i < 4; ++i)
            if (base + i < n) s += cnt[base + i];
    }
    __shared__ int red[256];
    red[tid] = s;
    __syncthreads();
    for (int st = 128; st > 0; st >>= 1) {
        if (tid < st) red[tid] += red[tid + st];
        __syncthreads();
    }
    if (tid == 0) blockSums[blockIdx.x] = red[0];
}

__global__ void k_scan2(int* __restrict__ blockSums, int* __restrict__ row_off,
                        int nb, int n) {
    __shared__ int s[256];
    int tid = threadIdx.x;  // 256
    int v = (tid < nb) ? blockSums[tid] : 0;
    s[tid] = v;
    __syncthreads();
    for (int off = 1; off < 256; off <<= 1) {
        int t = (tid >= off) ? s[tid - off] : 0;
        __syncthreads();
        s[tid] += t;
        __syncthreads();
    }
    if (tid < nb) blockSums[tid] = s[tid] - v;
    if (tid == 0) row_off[n] = s[255];
}

__global__ void k_scan3(const int* __restrict__ cnt, const int* __restrict__ blockOff,
                        int* __restrict__ row_off, int n) {
    int tid = threadIdx.x;  // 256
    int base = blockIdx.x * 1024 + tid * 4;
    int v[4];
    #pragma unroll
    for (int i = 0; i < 4; ++i) v[i] = (base + i < n) ? cnt[base + i] : 0;
    int local = v[0] + v[1] + v[2] + v[3];
    __shared__ int s[256];
    s[tid] = local;
    __syncthreads();
    for (int off = 1; off < 256; off <<= 1) {
        int t = (tid >= off) ? s[tid - off] : 0;
        __syncthreads();
        s[tid] += t;
        __syncthreads();
    }
    int excl = s[tid] - local + blockOff[blockIdx.x];
    #pragma unroll
    for (int i = 0; i < 4; ++i) {
        if (base + i < n) { row_off[base + i] = excl; excl += v[i]; }
    }
}

// bucketBase[b] = row_off[min(b*128, n)]; bucketCursor gets a working copy.
__global__ void k_binit(const int* __restrict__ row_off, int* __restrict__ bucketBase,
                        int* __restrict__ bucketCursor, int nbk, int n) {
    int b = blockIdx.x * 256 + threadIdx.x;
    if (b <= nbk) {
        int r = b << BSHIFT;
        if (r > n) r = n;
        int v = row_off[r];
        bucketBase[b] = v;
        if (b < nbk) bucketCursor[b] = v;
    }
}

// ---- two-pass scatter ------------------------------------------------------
// Why: single-pass per-row scatter showed 153 MB WRITE for 12.8 MB payload —
// consecutive csr positions are claimed by temporally-uncorrelated threads
// (a row's 16 claims span the dispatch), so each 64B line is evicted ~8x
// before it fills. With ~782 coarse bucket cursors, consecutive positions go
// to temporally-ADJACENT claimers -> lines fill while L2-resident (~1x).
// Pass 2 then places each bucket's entries into exact per-row positions
// inside a ~16 KB window (L2-resident) -> also ~1x writes.
// Entry in stage: {(col<<7) | (row & 127), val_bits}; bucket id is implicit
// from the position. Within-row edge order stays nondeterministic (as before).
__global__ void k_bucket(const int* __restrict__ erow, const int* __restrict__ ecol,
                         const float* __restrict__ eval_, int* __restrict__ bucketCursor,
                         int2* __restrict__ stage, int E) {
    int e = blockIdx.x * 256 + threadIdx.x;
    if (e < E) {
        int r = erow[e];
        int c = ecol[e];
        int pos = atomicAdd(&bucketCursor[r >> BSHIFT], 1);
        stage[pos] = make_int2((c << BSHIFT) | (r & 127), __float_as_int(eval_[e]));
    }
}

__global__ void k_place(const int2* __restrict__ stage, const int* __restrict__ bucketBase,
                        int* __restrict__ cursor, int2* __restrict__ csr_cv) {
    int b = blockIdx.x;
    int lo = bucketBase[b], hi = bucketBase[b + 1];
    int rbase = b << BSHIFT;
    for (int e = lo + threadIdx.x; e < hi; e += 256) {
        int2 s = stage[e];
        int r = rbase + (s.x & 127);
        int pos = atomicAdd(&cursor[r], 1);
        csr_cv[pos] = make_int2((s.x >> BSHIFT) << 8, s.y);
    }
}

// ---------------------------------------------------------------- fused SpMM + dense update
// (r5 champion, unchanged: 143 us/iter measured.)
// Phase 1: each 32-lane group gathers 4 rows of SY = S @ Yh into LDS (fp32),
//          unroll-8. Phase 2: Yout = (SY tile) @ G + anchor (bf16 Y0h iters
//          0..3, exact fp32 Y0 final). G from L1/L2. LDS 16 KB -> 8 blocks/CU.
//          Zero barriers on the non-final path.
__global__ void __launch_bounds__(256, 8) k_fused(const unsigned short* __restrict__ Yh,
                                                  const int* __restrict__ row_off,
                                                  const int2* __restrict__ csr_cv,
                                                  const float* __restrict__ G,
                                                  const float* __restrict__ Y0,
                                                  const unsigned short* __restrict__ Y0h,
                                                  float* __restrict__ Yout,
                                                  unsigned short* __restrict__ Yhout,
                                                  float* __restrict__ stats,
                                                  int writeH, int writeF, int n) {
    __shared__ float sSY[32 * MDIM];    // 16 KB (reused for BN partials at the end)
    int tid = threadIdx.x;
    int ty = tid >> 5;          // group 0..7
    int tx = tid & 31;          // lane-in-group, owns features tx*4..tx*4+3
    int rbase = blockIdx.x * 32;
    const char* yb = (const char*)Yh;
    int lbo = tx * 8;           // lane byte offset within a Yh row

    // ---- gather phase: group ty handles rows rbase + ty*4 .. +3
    for (int i = 0; i < 4; ++i) {
        int rloc = ty * 4 + i;
        int e0 = row_off[rbase + rloc];
        int e1 = row_off[rbase + rloc + 1];
        float4 a = make_float4(0.f, 0.f, 0.f, 0.f);
        int e = e0;
        for (; e + 8 <= e1; e += 8) {
            int2 p0 = csr_cv[e + 0];
            int2 p1 = csr_cv[e + 1];
            int2 p2 = csr_cv[e + 2];
            int2 p3 = csr_cv[e + 3];
            int2 p4 = csr_cv[e + 4];
            int2 p5 = csr_cv[e + 5];
            int2 p6 = csr_cv[e + 6];
            int2 p7 = csr_cv[e + 7];
            ushort4 h0 = *(const ushort4*)(yb + (size_t)(p0.x + lbo));
            ushort4 h1 = *(const ushort4*)(yb + (size_t)(p1.x + lbo));
            ushort4 h2 = *(const ushort4*)(yb + (size_t)(p2.x + lbo));
            ushort4 h3 = *(const ushort4*)(yb + (size_t)(p3.x + lbo));
            ushort4 h4 = *(const ushort4*)(yb + (size_t)(p4.x + lbo));
            ushort4 h5 = *(const ushort4*)(yb + (size_t)(p5.x + lbo));
            ushort4 h6 = *(const ushort4*)(yb + (size_t)(p6.x + lbo));
            ushort4 h7 = *(const ushort4*)(yb + (size_t)(p7.x + lbo));
            float v0 = __int_as_float(p0.y);
            float v1 = __int_as_float(p1.y);
            float v2 = __int_as_float(p2.y);
            float v3 = __int_as_float(p3.y);
            float v4 = __int_as_float(p4.y);
            float v5 = __int_as_float(p5.y);
            float v6 = __int_as_float(p6.y);
            float v7 = __int_as_float(p7.y);
            a.x = fmaf(v0, bf2f(h0.x), a.x);
            a.y = fmaf(v0, bf2f(h0.y), a.y);
            a.z = fmaf(v0, bf2f(h0.z), a.z);
            a.w = fmaf(v0, bf2f(h0.w), a.w);
            a.x = fmaf(v1, bf2f(h1.x), a.x);
            a.y = fmaf(v1, bf2f(h1.y), a.y);
            a.z = fmaf(v1, bf2f(h1.z), a.z);
            a.w = fmaf(v1, bf2f(h1.w), a.w);
            a.x = fmaf(v2, bf2f(h2.x), a.x);
            a.y = fmaf(v2, bf2f(h2.y), a.y);
            a.z = fmaf(v2, bf2f(h2.z), a.z);
            a.w = fmaf(v2, bf2f(h2.w), a.w);
            a.x = fmaf(v3, bf2f(h3.x), a.x);
            a.y = fmaf(v3, bf2f(h3.y), a.y);
            a.z = fmaf(v3, bf2f(h3.z), a.z);
            a.w = fmaf(v3, bf2f(h3.w), a.w);
            a.x = fmaf(v4, bf2f(h4.x), a.x);
            a.y = fmaf(v4, bf2f(h4.y), a.y);
            a.z = fmaf(v4, bf2f(h4.z), a.z);
            a.w = fmaf(v4, bf2f(h4.w), a.w);
            a.x = fmaf(v5, bf2f(h5.x), a.x);
            a.y = fmaf(v5, bf2f(h5.y), a.y);
            a.z = fmaf(v5, bf2f(h5.z), a.z);
            a.w = fmaf(v5, bf2f(h5.w), a.w);
            a.x = fmaf(v6, bf2f(h6.x), a.x);
            a.y = fmaf(v6, bf2f(h6.y), a.y);
            a.z = fmaf(v6, bf2f(h6.z), a.z);
            a.w = fmaf(v6, bf2f(h6.w), a.w);
            a.x = fmaf(v7, bf2f(h7.x), a.x);
            a.y = fmaf(v7, bf2f(h7.y), a.y);
            a.z = fmaf(v7, bf2f(h7.z), a.z);
            a.w = fmaf(v7, bf2f(h7.w), a.w);
        }
        for (; e + 4 <= e1; e += 4) {
            int2 p0 = csr_cv[e + 0];
            int2 p1 = csr_cv[e + 1];
            int2 p2 = csr_cv[e + 2];
            int2 p3 = csr_cv[e + 3];
            ushort4 h0 = *(const ushort4*)(yb + (size_t)(p0.x + lbo));
            ushort4 h1 = *(const ushort4*)(yb + (size_t)(p1.x + lbo));
            ushort4 h2 = *(const ushort4*)(yb + (size_t)(p2.x + lbo));
            ushort4 h3 = *(const ushort4*)(yb + (size_t)(p3.x + lbo));
            float v0 = __int_as_float(p0.y);
            float v1 = __int_as_float(p1.y);
            float v2 = __int_as_float(p2.y);
            float v3 = __int_as_float(p3.y);
            a.x = fmaf(v0, bf2f(h0.x), a.x);
            a.y = fmaf(v0, bf2f(h0.y), a.y);
            a.z = fmaf(v0, bf2f(h0.z), a.z);
            a.w = fmaf(v0, bf2f(h0.w), a.w);
            a.x = fmaf(v1, bf2f(h1.x), a.x);
            a.y = fmaf(v1, bf2f(h1.y), a.y);
            a.z = fmaf(v1, bf2f(h1.z), a.z);
            a.w = fmaf(v1, bf2f(h1.w), a.w);
            a.x = fmaf(v2, bf2f(h2.x), a.x);
            a.y = fmaf(v2, bf2f(h2.y), a.y);
            a.z = fmaf(v2, bf2f(h2.z), a.z);
            a.w = fmaf(v2, bf2f(h2.w), a.w);
            a.x = fmaf(v3, bf2f(h3.x), a.x);
            a.y = fmaf(v3, bf2f(h3.y), a.y);
            a.z = fmaf(v3, bf2f(h3.z), a.z);
            a.w = fmaf(v3, bf2f(h3.w), a.w);
        }
        for (; e < e1; ++e) {
            int2 p = csr_cv[e];
            float v = __int_as_float(p.y);
            ushort4 h = *(const ushort4*)(yb + (size_t)(p.x + lbo));
            a.x = fmaf(v, bf2f(h.x), a.x);
            a.y = fmaf(v, bf2f(h.y), a.y);
            a.z = fmaf(v, bf2f(h.z), a.z);
            a.w = fmaf(v, bf2f(h.w), a.w);
        }
        // dense phase reads these rows only from the same wave64 ->
        // intra-wave ordering suffices, no block barrier needed.
        *(float4*)&sSY[rloc * MDIM + tx * 4] = a;
    }

    // ---- dense phase: thread computes 4 rows x 4 features, G from L1/L2
    size_t r0 = (size_t)rbase + ty * 4;
    int f0 = tx * 4;
    float4 acc[4];
    #pragma unroll
    for (int i = 0; i < 4; ++i) acc[i] = make_float4(0.f, 0.f, 0.f, 0.f);

    for (int j = 0; j < MDIM; j += 4) {
        float4 g0 = *(const float4*)&G[(j + 0) * MDIM + f0];
        float4 g1 = *(const float4*)&G[(j + 1) * MDIM + f0];
        float4 g2 = *(const float4*)&G[(j + 2) * MDIM + f0];
        float4 g3 = *(const float4*)&G[(j + 3) * MDIM + f0];
        #pragma unroll
        for (int i = 0; i < 4; ++i) {
            float4 sr = *(const float4*)&sSY[(ty * 4 + i) * MDIM + j];
            acc[i].x = fmaf(sr.x, g0.x, acc[i].x);
            acc[i].y = fmaf(sr.x, g0.y, acc[i].y);
            acc[i].z = fmaf(sr.x, g0.z, acc[i].z);
            acc[i].w = fmaf(sr.x, g0.w, acc[i].w);
            acc[i].x = fmaf(sr.y, g1.x, acc[i].x);
            acc[i].y = fmaf(sr.y, g1.y, acc[i].y);
            acc[i].z = fmaf(sr.y, g1.z, acc[i].z);
            acc[i].w = fmaf(sr.y, g1.w, acc[i].w);
            acc[i].x = fmaf(sr.z, g2.x, acc[i].x);
            acc[i].y = fmaf(sr.z, g2.y, acc[i].y);
            acc[i].z = fmaf(sr.z, g2.z, acc[i].z);
            acc[i].w = fmaf(sr.z, g2.w, acc[i].w);
            acc[i].x = fmaf(sr.w, g3.x, acc[i].x);
            acc[i].y = fmaf(sr.w, g3.y, acc[i].y);
            acc[i].z = fmaf(sr.w, g3.z, acc[i].z);
            acc[i].w = fmaf(sr.w, g3.w, acc[i].w);
        }
    }

    float4 bs = make_float4(0.f, 0.f, 0.f, 0.f);
    float4 bq = make_float4(0.f, 0.f, 0.f, 0.f);
    #pragma unroll
    for (int i = 0; i < 4; ++i) {
        float4 y0;
        if (writeF) {
            y0 = *(const float4*)&Y0[(r0 + i) * MDIM + f0];
        } else {
            ushort4 t4 = *(const ushort4*)&Y0h[(r0 + i) * MDIM + f0];
            y0.x = bf2f(t4.x);
            y0.y = bf2f(t4.y);
            y0.z = bf2f(t4.z);
            y0.w = bf2f(t4.w);
        }
        float4 o;
        o.x = acc[i].x + y0.x;
        o.y = acc[i].y + y0.y;
        o.z = acc[i].z + y0.z;
        o.w = acc[i].w + y0.w;
        if (writeF) {
            *(float4*)&Yout[(r0 + i) * MDIM + f0] = o;
            bs.x += o.x; bs.y += o.y; bs.z += o.z; bs.w += o.w;
            bq.x = fmaf(o.x, o.x, bq.x);
            bq.y = fmaf(o.y, o.y, bq.y);
            bq.z = fmaf(o.z, o.z, bq.z);
            bq.w = fmaf(o.w, o.w, bq.w);
        }
        if (writeH) {
            ushort4 h;
            h.x = f2bf(o.x);
            h.y = f2bf(o.y);
            h.z = f2bf(o.z);
            h.w = f2bf(o.w);
            *(ushort4*)&Yhout[(r0 + i) * MDIM + f0] = h;
        }
    }

    // ---- fused BN partial stats (final iteration only)
    if (writeF) {
        __syncthreads();  // everyone done reading sSY
        *(float4*)&sSY[ty * MDIM + f0] = bs;
        *(float4*)&sSY[8 * MDIM + ty * MDIM + f0] = bq;
        __syncthreads();
        if (tid < MDIM) {
            float a = 0.f, b = 0.f;
            #pragma unroll
            for (int t = 0; t < 8; ++t) {
                a += sSY[t * MDIM + tid];
                b += sSY[8 * MDIM + t * MDIM + tid];
            }
            atomicAdd(&stats[tid], a);
            atomicAdd(&stats[MDIM + tid], b);
        }
    }
}

// ---------------------------------------------------------------- BN finalize
__global__ void k_finalize(const float* __restrict__ stats, const float* __restrict__ B,
                           const float* __restrict__ bnw, const float* __restrict__ bnb,
                           float* __restrict__ Bs, float* __restrict__ cvec, int n) {
    int f = threadIdx.x;
    float inv_n = 1.f / (float)n;
    float mu = stats[f] * inv_n;
    float var = stats[MDIM + f] * inv_n - mu * mu;
    float rs = rsqrtf(var + 1e-5f);
    float sw = rs * bnw[f];
    float cv = bnb[f] - mu * sw;
    __shared__ float red[MDIM];
    for (int o = 0; o < MY; ++o) {
        float b = B[o * MDIM + f];
        Bs[o * MDIM + f] = b * sw;
        red[f] = b * cv;
        __syncthreads();
        for (int s = 64; s > 0; s >>= 1) {
            if (f < s) red[f] += red[f + s];
            __syncthreads();
        }
        if (f == 0) cvec[o] = red[0];
        __syncthreads();
    }
}

// ---------------------------------------------------------------- projection
__global__ void __launch_bounds__(256) k_project(const float* __restrict__ Y,
                                                 const float* __restrict__ Bs,
                                                 const float* __restrict__ cvec,
                                                 float* __restrict__ out, int n) {
    __shared__ float yt[16 * 129];
    __shared__ float sB[MY * 129];
    __shared__ float sc[MY];
    int tid = threadIdx.x;
    size_t rbase = (size_t)blockIdx.x * 16;
    for (int idx = tid; idx < 16 * MDIM; idx += 256) {
        int r = idx >> 7, f = idx & 127;
        yt[r * 129 + f] = Y[(rbase + r) * MDIM + f];
    }
    for (int idx = tid; idx < MY * MDIM; idx += 256) {
        int o = idx >> 7, f = idx & 127;
        sB[o * 129 + f] = Bs[idx];
    }
    if (tid < MY) sc[tid] = cvec[tid];
    __syncthreads();
    if (tid < 16 * MY) {
        int r = tid / MY, o = tid % MY;
        float acc = sc[o];
        for (int f = 0; f < MDIM; ++f)
            acc = fmaf(yt[r * 129 + f], sB[o * 129 + f], acc);
        out[(rbase + r) * MY + o] = acc;
    }
}

// ---------------------------------------------------------------- launch
extern "C" void kernel_launch(void* const* d_in, const int* in_sizes, int n_in,
                              void* d_out, int out_size, void* d_ws, size_t ws_size,
                              hipStream_t stream) {
    const float* X    = (const float*)d_in[0];
    const float* F    = (const float*)d_in[1];
    const float* B    = (const float*)d_in[2];
    const float* bnw  = (const float*)d_in[3];
    const float* bnb  = (const float*)d_in[4];
    const float* ev   = (const float*)d_in[5];
    const int*   erow = (const int*)d_in[6];
    const int*   ecol = (const int*)d_in[7];
    float* out = (float*)d_out;
    const int n = in_sizes[0] / MDIM;  // 100000
    const int E = in_sizes[5];         // 1600000
    const int nbk = NBUCK(n);          // 782

    char* w = (char*)d_ws;
    size_t off = 0;
    auto carve = [&](size_t bytes) -> void* {
        void* p = w + off;
        off += (bytes + 255) & ~(size_t)255;
        return p;
    };
    float*          Y0    = (float*)carve((size_t)n * MDIM * 4);
    float*          Ycur  = (float*)carve((size_t)n * MDIM * 4);
    unsigned short* Y0h   = (unsigned short*)carve((size_t)n * MDIM * 2);  // bf16 anchor
    unsigned short* Yh_a  = (unsigned short*)carve((size_t)n * MDIM * 2);  // bf16 state ping
    unsigned short* Yh_b  = (unsigned short*)carve((size_t)n * MDIM * 2);  // bf16 state pong
    float* FF        = (float*)carve(MDIM * MDIM * 4);
    float* G         = (float*)carve(MDIM * MDIM * 4);
    int2*  csr_cv    = (int2*)carve((size_t)E * 8);
    int2*  stage     = (int2*)carve((size_t)E * 8);
    int*   row_off   = (int*)carve((size_t)(n + 1) * 4);
    int*   cursor    = (int*)carve((size_t)n * 4);
    int*   cnt       = (int*)carve((size_t)n * 4);
    int*   blockSums = (int*)carve(1024 * 4);
    int*   bucketBase   = (int*)carve((size_t)(nbk + 1) * 4);
    int*   bucketCursor = (int*)carve((size_t)nbk * 4);
    float* normAcc   = (float*)carve(4);
    float* stats     = (float*)carve(2 * MDIM * 4);
    float* Bs        = (float*)carve(MY * MDIM * 4);
    float* cvec      = (float*)carve(MY * 4);
    (void)ws_size;

    hipMemsetAsync(cnt, 0, (size_t)n * 4, stream);
    hipMemsetAsync(normAcc, 0, 4, stream);
    hipMemsetAsync(stats, 0, 2 * MDIM * 4, stream);

    k_transpose<<<dim3(n / 32, MDIM / 32), dim3(32, 8), 0, stream>>>(X, Y0, Y0h, Yh_a, n);
    k_gram<<<MDIM, MDIM, 0, stream>>>(F, FF, normAcc);
    k_gnorm<<<MDIM * MDIM / 256, 256, 0, stream>>>(FF, normAcc, G);

    const int nb = (n + 1023) / 1024;
    k_hist<<<(E + 255) / 256, 256, 0, stream>>>(erow, cnt, E);
    k_scan1<<<nb, 256, 0, stream>>>(cnt, blockSums, n);
    k_scan2<<<1, 256, 0, stream>>>(blockSums, row_off, nb, n);
    k_scan3<<<nb, 256, 0, stream>>>(cnt, blockSums, row_off, n);
    k_binit<<<(nbk + 256) / 256, 256, 0, stream>>>(row_off, bucketBase, bucketCursor, nbk, n);
    hipMemcpyAsync(cursor, row_off, (size_t)n * 4, hipMemcpyDeviceToDevice, stream);
    k_bucket<<<(E + 255) / 256, 256, 0, stream>>>(erow, ecol, ev, bucketCursor, stage, E);
    k_place<<<nbk, 256, 0, stream>>>(stage, bucketBase, cursor, csr_cv);

    for (int k = 0; k < KITER; ++k) {
        const unsigned short* hin = (k & 1) ? Yh_b : Yh_a;
        unsigned short*       hout = (k & 1) ? Yh_a : Yh_b;
        int writeH = (k < KITER - 1) ? 1 : 0;
        int writeF = (k == KITER - 1) ? 1 : 0;
        k_fused<<<(n + 31) / 32, 256, 0, stream>>>(hin, row_off, csr_cv, G, Y0, Y0h,
                                                   Ycur, hout, stats, writeH, writeF, n);
    }

    k_finalize<<<1, MDIM, 0, stream>>>(stats, B, bnw, bnb, Bs, cvec, n);
    k_project<<<n / 16, 256, 0, stream>>>(Ycur, Bs, cvec, out, n);
}

// Round 9
// 1154.115 us; speedup vs baseline: 1.3122x; 1.0767x over previous
//
#include <hip/hip_runtime.h>
#include <math.h>

#define MDIM 128
#define MY 10
#define GAMMA 0.8f
#define KITER 5

__device__ __forceinline__ float bf2f(unsigned short h) {
    return __uint_as_float(((unsigned int)h) << 16);
}
__device__ __forceinline__ unsigned short f2bf(float f) {
    unsigned int u = __float_as_uint(f);
    u += 0x7fffu + ((u >> 16) & 1u);  // round-to-nearest-even
    return (unsigned short)(u >> 16);
}

// ---------------------------------------------------------------- transpose
// X [128][n] -> Y0 fp32 [n][128], Y0h bf16 anchor (persistent), Yh bf16 state
__global__ void k_transpose(const float* __restrict__ X, float* __restrict__ Y0,
                            unsigned short* __restrict__ Y0h,
                            unsigned short* __restrict__ Yh0, int n) {
    __shared__ float tile[32][33];
    int r0 = blockIdx.x * 32;
    int f0 = blockIdx.y * 32;
    int tx = threadIdx.x, ty = threadIdx.y;  // 32 x 8
    #pragma unroll
    for (int i = 0; i < 32; i += 8) {
        tile[ty + i][tx] = X[(size_t)(f0 + ty + i) * n + (r0 + tx)];
    }
    __syncthreads();
    #pragma unroll
    for (int i = 0; i < 32; i += 8) {
        float v = tile[tx][ty + i];
        unsigned short h = f2bf(v);
        Y0[(size_t)(r0 + ty + i) * MDIM + (f0 + tx)] = v;
        Y0h[(size_t)(r0 + ty + i) * MDIM + (f0 + tx)] = h;
        Yh0[(size_t)(r0 + ty + i) * MDIM + (f0 + tx)] = h;
    }
}

// ---------------------------------------------------------------- Gram matrix
__global__ void k_gram(const float* __restrict__ F, float* __restrict__ FF,
                       float* __restrict__ normAcc) {
    int i = blockIdx.x, j = threadIdx.x;
    float acc = 0.f;
    for (int k = 0; k < MDIM; ++k)
        acc = fmaf(F[k * MDIM + i], F[k * MDIM + j], acc);
    FF[i * MDIM + j] = acc;
    __shared__ float red[MDIM];
    red[j] = acc * acc;
    __syncthreads();
    for (int s = 64; s > 0; s >>= 1) {
        if (j < s) red[j] += red[j + s];
        __syncthreads();
    }
    if (j == 0) atomicAdd(normAcc, red[0]);
}

__global__ void k_gnorm(const float* __restrict__ FF, const float* __restrict__ normAcc,
                        float* __restrict__ G) {
    int idx = blockIdx.x * 256 + threadIdx.x;
    float s = GAMMA / (sqrtf(*normAcc) + 1e-6f);
    G[idx] = FF[idx] * s;
}

// ---------------------------------------------------------------- CSR build (per-row hist/scan)
__global__ void k_hist(const int* __restrict__ erow, int* __restrict__ cnt, int E) {
    int e = blockIdx.x * 256 + threadIdx.x;
    if (e < E) atomicAdd(&cnt[erow[e]], 1);
}

__global__ void k_scan1(const int* __restrict__ cnt, int* __restrict__ blockSums, int n) {
    int tid = threadIdx.x;  // 256
    int base = blockIdx.x * 1024 + tid * 4;
    int s = 0;
    if (base + 3 < n) {
        int4 v = *(const int4*)&cnt[base];
        s = v.x + v.y + v.z + v.w;
    } else {
        for (int i = 0; i < 4; ++i)
            if (base + i < n) s += cnt[base + i];
    }
    __shared__ int red[256];
    red[tid] = s;
    __syncthreads();
    for (int st = 128; st > 0; st >>= 1) {
        if (tid < st) red[tid] += red[tid + st];
        __syncthreads();
    }
    if (tid == 0) blockSums[blockIdx.x] = red[0];
}

__global__ void k_scan2(int* __restrict__ blockSums, int* __restrict__ row_off,
                        int nb, int n) {
    __shared__ int s[256];
    int tid = threadIdx.x;  // 256
    int v = (tid < nb) ? blockSums[tid] : 0;
    s[tid] = v;
    __syncthreads();
    for (int off = 1; off < 256; off <<= 1) {
        int t = (tid >= off) ? s[tid - off] : 0;
        __syncthreads();
        s[tid] += t;
        __syncthreads();
    }
    if (tid < nb) blockSums[tid] = s[tid] - v;
    if (tid == 0) row_off[n] = s[255];
}

__global__ void k_scan3(const int* __restrict__ cnt, const int* __restrict__ blockOff,
                        int* __restrict__ row_off, int n) {
    int tid = threadIdx.x;  // 256
    int base = blockIdx.x * 1024 + tid * 4;
    int v[4];
    #pragma unroll
    for (int i = 0; i < 4; ++i) v[i] = (base + i < n) ? cnt[base + i] : 0;
    int local = v[0] + v[1] + v[2] + v[3];
    __shared__ int s[256];
    s[tid] = local;
    __syncthreads();
    for (int off = 1; off < 256; off <<= 1) {
        int t = (tid >= off) ? s[tid - off] : 0;
        __syncthreads();
        s[tid] += t;
        __syncthreads();
    }
    int excl = s[tid] - local + blockOff[blockIdx.x];
    #pragma unroll
    for (int i = 0; i < 4; ++i) {
        if (base + i < n) { row_off[base + i] = excl; excl += v[i]; }
    }
}

// cursorB[b] = row_off[4b]  (bucket b = rows 4b..4b+3; bko[b] == row_off[4b])
__global__ void k_cinit(const int* __restrict__ row_off, int* __restrict__ cursorB, int nbk) {
    int b = blockIdx.x * 256 + threadIdx.x;
    if (b < nbk) cursorB[b] = row_off[b << 2];
}

// 4-row-bucket scatter: 25K cursors. Contention chains ~64x440cyc = 12us (ok,
// vs 782-cursor version's 0.9ms chains), and consecutive positions in a bucket
// are claimed by temporally-adjacent threads -> scattered-store lines fill
// while L2-resident (~1x writeback vs 12x with per-row cursors).
// Entry {(col<<8) | (row&3), val_bits}: tag rides in the low bits of the
// 256-aligned column byte offset. Within-bucket order nondeterministic (same
// class as the old per-row atomic order).
__global__ void k_scatter(const int* __restrict__ erow, const int* __restrict__ ecol,
                          const float* __restrict__ eval_, int* __restrict__ cursorB,
                          int2* __restrict__ csr_cv, int E) {
    int e = blockIdx.x * 256 + threadIdx.x;
    if (e < E) {
        int r = erow[e];
        int c = ecol[e];
        int pos = atomicAdd(&cursorB[r >> 2], 1);
        csr_cv[pos] = make_int2((c << 8) | (r & 3), __float_as_int(eval_[e]));
    }
}

// one edge for the wave-per-bucket gather: 64 lanes x 4B cover the source row;
// rid is wave-uniform (all lanes read the same csr entry) -> readfirstlane
// scalarizes it so the 4-way dispatch is s_cbranch (no divergence).
#define EDGE(p, h, A0, A1, A2, A3)                                          \
    {                                                                       \
        float v = __int_as_float(p.y);                                      \
        float f0 = __uint_as_float(((unsigned)h) << 16);                    \
        float f1 = __uint_as_float(((unsigned)h) & 0xFFFF0000u);            \
        int rid = __builtin_amdgcn_readfirstlane(p.x) & 3;                  \
        if (rid == 0)      { A0.x = fmaf(v, f0, A0.x); A0.y = fmaf(v, f1, A0.y); } \
        else if (rid == 1) { A1.x = fmaf(v, f0, A1.x); A1.y = fmaf(v, f1, A1.y); } \
        else if (rid == 2) { A2.x = fmaf(v, f0, A2.x); A2.y = fmaf(v, f1, A2.y); } \
        else               { A3.x = fmaf(v, f0, A3.x); A3.y = fmaf(v, f1, A3.y); } \
    }

#define GATHER_BUCKET(BK, A0, A1, A2, A3)                                   \
    {                                                                       \
        int e  = row_off[(BK) << 2];                                        \
        int e1 = row_off[((BK) << 2) + 4];                                  \
        for (; e + 8 <= e1; e += 8) {                                       \
            int2 p0 = csr_cv[e + 0]; int2 p1 = csr_cv[e + 1];               \
            int2 p2 = csr_cv[e + 2]; int2 p3 = csr_cv[e + 3];               \
            int2 p4 = csr_cv[e + 4]; int2 p5 = csr_cv[e + 5];               \
            int2 p6 = csr_cv[e + 6]; int2 p7 = csr_cv[e + 7];               \
            unsigned h0 = *(const unsigned*)(yb + (size_t)((p0.x & 0xFFFFFF00) + lbo)); \
            unsigned h1 = *(const unsigned*)(yb + (size_t)((p1.x & 0xFFFFFF00) + lbo)); \
            unsigned h2 = *(const unsigned*)(yb + (size_t)((p2.x & 0xFFFFFF00) + lbo)); \
            unsigned h3 = *(const unsigned*)(yb + (size_t)((p3.x & 0xFFFFFF00) + lbo)); \
            unsigned h4 = *(const unsigned*)(yb + (size_t)((p4.x & 0xFFFFFF00) + lbo)); \
            unsigned h5 = *(const unsigned*)(yb + (size_t)((p5.x & 0xFFFFFF00) + lbo)); \
            unsigned h6 = *(const unsigned*)(yb + (size_t)((p6.x & 0xFFFFFF00) + lbo)); \
            unsigned h7 = *(const unsigned*)(yb + (size_t)((p7.x & 0xFFFFFF00) + lbo)); \
            EDGE(p0, h0, A0, A1, A2, A3) EDGE(p1, h1, A0, A1, A2, A3)       \
            EDGE(p2, h2, A0, A1, A2, A3) EDGE(p3, h3, A0, A1, A2, A3)       \
            EDGE(p4, h4, A0, A1, A2, A3) EDGE(p5, h5, A0, A1, A2, A3)       \
            EDGE(p6, h6, A0, A1, A2, A3) EDGE(p7, h7, A0, A1, A2, A3)       \
        }                                                                   \
        for (; e < e1; ++e) {                                               \
            int2 p = csr_cv[e];                                             \
            unsigned h = *(const unsigned*)(yb + (size_t)((p.x & 0xFFFFFF00) + lbo)); \
            EDGE(p, h, A0, A1, A2, A3)                                      \
        }                                                                   \
    }

// ---------------------------------------------------------------- fused SpMM + dense update
// Gather: wave w handles buckets 2w, 2w+1 (= block-local rows 8w..8w+7);
// each lane owns features lane*2..lane*2+1 (4 B) of every gathered row.
// Dense phase, anchor handling, BN fusion: identical to the r5 champion
// (32-row tile, 16 KB LDS, 8 blocks/CU, zero barriers on non-final path —
// dense group ty reads rows 4ty..4ty+3, which wave w=ty/2 itself wrote).
__global__ void __launch_bounds__(256, 8) k_fused(const unsigned short* __restrict__ Yh,
                                                  const int* __restrict__ row_off,
                                                  const int2* __restrict__ csr_cv,
                                                  const float* __restrict__ G,
                                                  const float* __restrict__ Y0,
                                                  const unsigned short* __restrict__ Y0h,
                                                  float* __restrict__ Yout,
                                                  unsigned short* __restrict__ Yhout,
                                                  float* __restrict__ stats,
                                                  int writeH, int writeF, int n) {
    __shared__ float sSY[32 * MDIM];    // 16 KB (reused for BN partials at the end)
    int tid = threadIdx.x;
    int lane = tid & 63;
    int w = tid >> 6;                   // wave 0..3
    int rbase = blockIdx.x * 32;
    const char* yb = (const char*)Yh;
    int lbo = lane * 4;                 // lane byte offset (2 bf16 features)

    float2 z = make_float2(0.f, 0.f);
    float2 a0 = z, a1 = z, a2 = z, a3 = z;   // bucket 2w   (rows 8w..8w+3)
    float2 b0 = z, b1 = z, b2 = z, b3 = z;   // bucket 2w+1 (rows 8w+4..8w+7)

    int bk0 = (rbase >> 2) + 2 * w;
    GATHER_BUCKET(bk0,     a0, a1, a2, a3)
    GATHER_BUCKET(bk0 + 1, b0, b1, b2, b3)

    // same-wave produce/consume -> no barrier needed before dense phase
    *(float2*)&sSY[(w * 8 + 0) * MDIM + lane * 2] = a0;
    *(float2*)&sSY[(w * 8 + 1) * MDIM + lane * 2] = a1;
    *(float2*)&sSY[(w * 8 + 2) * MDIM + lane * 2] = a2;
    *(float2*)&sSY[(w * 8 + 3) * MDIM + lane * 2] = a3;
    *(float2*)&sSY[(w * 8 + 4) * MDIM + lane * 2] = b0;
    *(float2*)&sSY[(w * 8 + 5) * MDIM + lane * 2] = b1;
    *(float2*)&sSY[(w * 8 + 6) * MDIM + lane * 2] = b2;
    *(float2*)&sSY[(w * 8 + 7) * MDIM + lane * 2] = b3;

    // ---- dense phase: thread computes 4 rows x 4 features, G from L1/L2
    int ty = tid >> 5;          // group 0..7 -> rows ty*4..ty*4+3 (wave ty/2 wrote them)
    int tx = tid & 31;
    size_t r0 = (size_t)rbase + ty * 4;
    int f0 = tx * 4;
    float4 acc[4];
    #pragma unroll
    for (int i = 0; i < 4; ++i) acc[i] = make_float4(0.f, 0.f, 0.f, 0.f);

    for (int j = 0; j < MDIM; j += 4) {
        float4 g0 = *(const float4*)&G[(j + 0) * MDIM + f0];
        float4 g1 = *(const float4*)&G[(j + 1) * MDIM + f0];
        float4 g2 = *(const float4*)&G[(j + 2) * MDIM + f0];
        float4 g3 = *(const float4*)&G[(j + 3) * MDIM + f0];
        #pragma unroll
        for (int i = 0; i < 4; ++i) {
            float4 sr = *(const float4*)&sSY[(ty * 4 + i) * MDIM + j];
            acc[i].x = fmaf(sr.x, g0.x, acc[i].x);
            acc[i].y = fmaf(sr.x, g0.y, acc[i].y);
            acc[i].z = fmaf(sr.x, g0.z, acc[i].z);
            acc[i].w = fmaf(sr.x, g0.w, acc[i].w);
            acc[i].x = fmaf(sr.y, g1.x, acc[i].x);
            acc[i].y = fmaf(sr.y, g1.y, acc[i].y);
            acc[i].z = fmaf(sr.y, g1.z, acc[i].z);
            acc[i].w = fmaf(sr.y, g1.w, acc[i].w);
            acc[i].x = fmaf(sr.z, g2.x, acc[i].x);
            acc[i].y = fmaf(sr.z, g2.y, acc[i].y);
            acc[i].z = fmaf(sr.z, g2.z, acc[i].z);
            acc[i].w = fmaf(sr.z, g2.w, acc[i].w);
            acc[i].x = fmaf(sr.w, g3.x, acc[i].x);
            acc[i].y = fmaf(sr.w, g3.y, acc[i].y);
            acc[i].z = fmaf(sr.w, g3.z, acc[i].z);
            acc[i].w = fmaf(sr.w, g3.w, acc[i].w);
        }
    }

    float4 bs = make_float4(0.f, 0.f, 0.f, 0.f);
    float4 bq = make_float4(0.f, 0.f, 0.f, 0.f);
    #pragma unroll
    for (int i = 0; i < 4; ++i) {
        float4 y0;
        if (writeF) {
            y0 = *(const float4*)&Y0[(r0 + i) * MDIM + f0];
        } else {
            ushort4 t4 = *(const ushort4*)&Y0h[(r0 + i) * MDIM + f0];
            y0.x = bf2f(t4.x);
            y0.y = bf2f(t4.y);
            y0.z = bf2f(t4.z);
            y0.w = bf2f(t4.w);
        }
        float4 o;
        o.x = acc[i].x + y0.x;
        o.y = acc[i].y + y0.y;
        o.z = acc[i].z + y0.z;
        o.w = acc[i].w + y0.w;
        if (writeF) {
            *(float4*)&Yout[(r0 + i) * MDIM + f0] = o;
            bs.x += o.x; bs.y += o.y; bs.z += o.z; bs.w += o.w;
            bq.x = fmaf(o.x, o.x, bq.x);
            bq.y = fmaf(o.y, o.y, bq.y);
            bq.z = fmaf(o.z, o.z, bq.z);
            bq.w = fmaf(o.w, o.w, bq.w);
        }
        if (writeH) {
            ushort4 h;
            h.x = f2bf(o.x);
            h.y = f2bf(o.y);
            h.z = f2bf(o.z);
            h.w = f2bf(o.w);
            *(ushort4*)&Yhout[(r0 + i) * MDIM + f0] = h;
        }
    }

    // ---- fused BN partial stats (final iteration only)
    if (writeF) {
        __syncthreads();  // everyone done reading sSY
        *(float4*)&sSY[ty * MDIM + f0] = bs;
        *(float4*)&sSY[8 * MDIM + ty * MDIM + f0] = bq;
        __syncthreads();
        if (tid < MDIM) {
            float a = 0.f, b = 0.f;
            #pragma unroll
            for (int t = 0; t < 8; ++t) {
                a += sSY[t * MDIM + tid];
                b += sSY[8 * MDIM + t * MDIM + tid];
            }
            atomicAdd(&stats[tid], a);
            atomicAdd(&stats[MDIM + tid], b);
        }
    }
}

// ---------------------------------------------------------------- BN finalize
__global__ void k_finalize(const float* __restrict__ stats, const float* __restrict__ B,
                           const float* __restrict__ bnw, const float* __restrict__ bnb,
                           float* __restrict__ Bs, float* __restrict__ cvec, int n) {
    int f = threadIdx.x;
    float inv_n = 1.f / (float)n;
    float mu = stats[f] * inv_n;
    float var = stats[MDIM + f] * inv_n - mu * mu;
    float rs = rsqrtf(var + 1e-5f);
    float sw = rs * bnw[f];
    float cv = bnb[f] - mu * sw;
    __shared__ float red[MDIM];
    for (int o = 0; o < MY; ++o) {
        float b = B[o * MDIM + f];
        Bs[o * MDIM + f] = b * sw;
        red[f] = b * cv;
        __syncthreads();
        for (int s = 64; s > 0; s >>= 1) {
            if (f < s) red[f] += red[f + s];
            __syncthreads();
        }
        if (f == 0) cvec[o] = red[0];
        __syncthreads();
    }
}

// ---------------------------------------------------------------- projection
__global__ void __launch_bounds__(256) k_project(const float* __restrict__ Y,
                                                 const float* __restrict__ Bs,
                                                 const float* __restrict__ cvec,
                                                 float* __restrict__ out, int n) {
    __shared__ float yt[16 * 129];
    __shared__ float sB[MY * 129];
    __shared__ float sc[MY];
    int tid = threadIdx.x;
    size_t rbase = (size_t)blockIdx.x * 16;
    for (int idx = tid; idx < 16 * MDIM; idx += 256) {
        int r = idx >> 7, f = idx & 127;
        yt[r * 129 + f] = Y[(rbase + r) * MDIM + f];
    }
    for (int idx = tid; idx < MY * MDIM; idx += 256) {
        int o = idx >> 7, f = idx & 127;
        sB[o * 129 + f] = Bs[idx];
    }
    if (tid < MY) sc[tid] = cvec[tid];
    __syncthreads();
    if (tid < 16 * MY) {
        int r = tid / MY, o = tid % MY;
        float acc = sc[o];
        for (int f = 0; f < MDIM; ++f)
            acc = fmaf(yt[r * 129 + f], sB[o * 129 + f], acc);
        out[(rbase + r) * MY + o] = acc;
    }
}

// ---------------------------------------------------------------- launch
extern "C" void kernel_launch(void* const* d_in, const int* in_sizes, int n_in,
                              void* d_out, int out_size, void* d_ws, size_t ws_size,
                              hipStream_t stream) {
    const float* X    = (const float*)d_in[0];
    const float* F    = (const float*)d_in[1];
    const float* B    = (const float*)d_in[2];
    const float* bnw  = (const float*)d_in[3];
    const float* bnb  = (const float*)d_in[4];
    const float* ev   = (const float*)d_in[5];
    const int*   erow = (const int*)d_in[6];
    const int*   ecol = (const int*)d_in[7];
    float* out = (float*)d_out;
    const int n = in_sizes[0] / MDIM;  // 100000
    const int E = in_sizes[5];         // 1600000
    const int nbk = (n + 3) / 4;       // 25000 4-row buckets

    char* w = (char*)d_ws;
    size_t off = 0;
    auto carve = [&](size_t bytes) -> void* {
        void* p = w + off;
        off += (bytes + 255) & ~(size_t)255;
        return p;
    };
    float*          Y0    = (float*)carve((size_t)n * MDIM * 4);
    float*          Ycur  = (float*)carve((size_t)n * MDIM * 4);
    unsigned short* Y0h   = (unsigned short*)carve((size_t)n * MDIM * 2);  // bf16 anchor
    unsigned short* Yh_a  = (unsigned short*)carve((size_t)n * MDIM * 2);  // bf16 state ping
    unsigned short* Yh_b  = (unsigned short*)carve((size_t)n * MDIM * 2);  // bf16 state pong
    float* FF        = (float*)carve(MDIM * MDIM * 4);
    float* G         = (float*)carve(MDIM * MDIM * 4);
    int2*  csr_cv    = (int2*)carve((size_t)E * 8);
    int*   row_off   = (int*)carve((size_t)(n + 1) * 4);
    int*   cursorB   = (int*)carve((size_t)nbk * 4);
    int*   cnt       = (int*)carve((size_t)n * 4);
    int*   blockSums = (int*)carve(1024 * 4);
    float* normAcc   = (float*)carve(4);
    float* stats     = (float*)carve(2 * MDIM * 4);
    float* Bs        = (float*)carve(MY * MDIM * 4);
    float* cvec      = (float*)carve(MY * 4);
    (void)ws_size;

    hipMemsetAsync(cnt, 0, (size_t)n * 4, stream);
    hipMemsetAsync(normAcc, 0, 4, stream);
    hipMemsetAsync(stats, 0, 2 * MDIM * 4, stream);

    k_transpose<<<dim3(n / 32, MDIM / 32), dim3(32, 8), 0, stream>>>(X, Y0, Y0h, Yh_a, n);
    k_gram<<<MDIM, MDIM, 0, stream>>>(F, FF, normAcc);
    k_gnorm<<<MDIM * MDIM / 256, 256, 0, stream>>>(FF, normAcc, G);

    const int nb = (n + 1023) / 1024;
    k_hist<<<(E + 255) / 256, 256, 0, stream>>>(erow, cnt, E);
    k_scan1<<<nb, 256, 0, stream>>>(cnt, blockSums, n);
    k_scan2<<<1, 256, 0, stream>>>(blockSums, row_off, nb, n);
    k_scan3<<<nb, 256, 0, stream>>>(cnt, blockSums, row_off, n);
    k_cinit<<<(nbk + 255) / 256, 256, 0, stream>>>(row_off, cursorB, nbk);
    k_scatter<<<(E + 255) / 256, 256, 0, stream>>>(erow, ecol, ev, cursorB, csr_cv, E);

    for (int k = 0; k < KITER; ++k) {
        const unsigned short* hin = (k & 1) ? Yh_b : Yh_a;
        unsigned short*       hout = (k & 1) ? Yh_a : Yh_b;
        int writeH = (k < KITER - 1) ? 1 : 0;
        int writeF = (k == KITER - 1) ? 1 : 0;
        k_fused<<<(n + 31) / 32, 256, 0, stream>>>(hin, row_off, csr_cv, G, Y0, Y0h,
                                                   Ycur, hout, stats, writeH, writeF, n);
    }

    k_finalize<<<1, MDIM, 0, stream>>>(stats, B, bnw, bnb, Bs, cvec, n);
    k_project<<<n / 16, 256, 0, stream>>>(Ycur, Bs, cvec, out, n);
}

// Round 10
// 1008.310 us; speedup vs baseline: 1.5020x; 1.1446x over previous
//
#include <hip/hip_runtime.h>
#include <math.h>

#define MDIM 128
#define MY 10
#define GAMMA 0.8f
#define KITER 5

__device__ __forceinline__ float bf2f(unsigned short h) {
    return __uint_as_float(((unsigned int)h) << 16);
}
__device__ __forceinline__ unsigned short f2bf(float f) {
    unsigned int u = __float_as_uint(f);
    u += 0x7fffu + ((u >> 16) & 1u);  // round-to-nearest-even
    return (unsigned short)(u >> 16);
}
// non-temporal 8B load: the csr stream has no reuse within a dispatch, so
// keep it from evicting gather lines out of L2.
__device__ __forceinline__ int2 ldnt(const int2* p) {
    long long v = __builtin_nontemporal_load((const long long*)p);
    int2 r;
    r.x = (int)(v & 0xFFFFFFFFLL);
    r.y = (int)(v >> 32);
    return r;
}

// ---------------------------------------------------------------- transpose
// X [128][n] -> Y0 fp32 [n][128], Y0h bf16 anchor (persistent), Yh bf16 state
__global__ void k_transpose(const float* __restrict__ X, float* __restrict__ Y0,
                            unsigned short* __restrict__ Y0h,
                            unsigned short* __restrict__ Yh0, int n) {
    __shared__ float tile[32][33];
    int r0 = blockIdx.x * 32;
    int f0 = blockIdx.y * 32;
    int tx = threadIdx.x, ty = threadIdx.y;  // 32 x 8
    #pragma unroll
    for (int i = 0; i < 32; i += 8) {
        tile[ty + i][tx] = X[(size_t)(f0 + ty + i) * n + (r0 + tx)];
    }
    __syncthreads();
    #pragma unroll
    for (int i = 0; i < 32; i += 8) {
        float v = tile[tx][ty + i];
        unsigned short h = f2bf(v);
        Y0[(size_t)(r0 + ty + i) * MDIM + (f0 + tx)] = v;
        Y0h[(size_t)(r0 + ty + i) * MDIM + (f0 + tx)] = h;
        Yh0[(size_t)(r0 + ty + i) * MDIM + (f0 + tx)] = h;
    }
}

// ---------------------------------------------------------------- Gram matrix
__global__ void k_gram(const float* __restrict__ F, float* __restrict__ FF,
                       float* __restrict__ normAcc) {
    int i = blockIdx.x, j = threadIdx.x;
    float acc = 0.f;
    for (int k = 0; k < MDIM; ++k)
        acc = fmaf(F[k * MDIM + i], F[k * MDIM + j], acc);
    FF[i * MDIM + j] = acc;
    __shared__ float red[MDIM];
    red[j] = acc * acc;
    __syncthreads();
    for (int s = 64; s > 0; s >>= 1) {
        if (j < s) red[j] += red[j + s];
        __syncthreads();
    }
    if (j == 0) atomicAdd(normAcc, red[0]);
}

__global__ void k_gnorm(const float* __restrict__ FF, const float* __restrict__ normAcc,
                        float* __restrict__ G) {
    int idx = blockIdx.x * 256 + threadIdx.x;
    float s = GAMMA / (sqrtf(*normAcc) + 1e-6f);
    G[idx] = FF[idx] * s;
}

// ---------------------------------------------------------------- CSR build (plain row CSR)
__global__ void k_hist(const int* __restrict__ erow, int* __restrict__ cnt, int E) {
    int e = blockIdx.x * 256 + threadIdx.x;
    if (e < E) atomicAdd(&cnt[erow[e]], 1);
}

__global__ void k_scan1(const int* __restrict__ cnt, int* __restrict__ blockSums, int n) {
    int tid = threadIdx.x;  // 256
    int base = blockIdx.x * 1024 + tid * 4;
    int s = 0;
    if (base + 3 < n) {
        int4 v = *(const int4*)&cnt[base];
        s = v.x + v.y + v.z + v.w;
    } else {
        for (int i = 0; i < 4; ++i)
            if (base + i < n) s += cnt[base + i];
    }
    __shared__ int red[256];
    red[tid] = s;
    __syncthreads();
    for (int st = 128; st > 0; st >>= 1) {
        if (tid < st) red[tid] += red[tid + st];
        __syncthreads();
    }
    if (tid == 0) blockSums[blockIdx.x] = red[0];
}

__global__ void k_scan2(int* __restrict__ blockSums, int* __restrict__ row_off,
                        int nb, int n) {
    __shared__ int s[256];
    int tid = threadIdx.x;  // 256
    int v = (tid < nb) ? blockSums[tid] : 0;
    s[tid] = v;
    __syncthreads();
    for (int off = 1; off < 256; off <<= 1) {
        int t = (tid >= off) ? s[tid - off] : 0;
        __syncthreads();
        s[tid] += t;
        __syncthreads();
    }
    if (tid < nb) blockSums[tid] = s[tid] - v;
    if (tid == 0) row_off[n] = s[255];
}

// writes row_off AND the scatter cursor copy (kills the D2D memcpy dispatch)
__global__ void k_scan3(const int* __restrict__ cnt, const int* __restrict__ blockOff,
                        int* __restrict__ row_off, int* __restrict__ cursor, int n) {
    int tid = threadIdx.x;  // 256
    int base = blockIdx.x * 1024 + tid * 4;
    int v[4];
    #pragma unroll
    for (int i = 0; i < 4; ++i) v[i] = (base + i < n) ? cnt[base + i] : 0;
    int local = v[0] + v[1] + v[2] + v[3];
    __shared__ int s[256];
    s[tid] = local;
    __syncthreads();
    for (int off = 1; off < 256; off <<= 1) {
        int t = (tid >= off) ? s[tid - off] : 0;
        __syncthreads();
        s[tid] += t;
        __syncthreads();
    }
    int excl = s[tid] - local + blockOff[blockIdx.x];
    #pragma unroll
    for (int i = 0; i < 4; ++i) {
        if (base + i < n) {
            row_off[base + i] = excl;
            cursor[base + i] = excl;
            excl += v[i];
        }
    }
}

// Single-pass per-row scatter (best measured variant; 8-pass and bucket
// schemes both regressed). Packed entry {col_byte_offset, val}.
__global__ void k_scatter(const int* __restrict__ erow, const int* __restrict__ ecol,
                          const float* __restrict__ eval_, int* __restrict__ cursor,
                          int2* __restrict__ csr_cv, int E) {
    int e = blockIdx.x * 256 + threadIdx.x;
    if (e < E) {
        int r = erow[e];
        int c = ecol[e];
        int pos = atomicAdd(&cursor[r], 1);
        csr_cv[pos] = make_int2(c << 8, __float_as_int(eval_[e]));
    }
}

// ---------------------------------------------------------------- fused SpMM + dense update
// (r5 champion structure: group-per-row gather, ushort4 loads, unroll-8,
//  143 us/iter measured — all locality/bucketing alternatives lost to it.)
// Phase 1: each 32-lane group gathers 4 rows of SY = S @ Yh into LDS (fp32).
// Phase 2: Yout = (SY tile) @ G + anchor. Anchor = bf16 Y0h iters 0..3,
//          exact fp32 Y0 on the final iter (feeds exact BN stats).
// Output: bf16 state EVERY iteration (final bf16 state feeds k_project);
//         no fp32 output array at all. BN partial stats fused on final iter.
// LDS 16 KB -> 8 blocks/CU; zero barriers on the non-final path.
__global__ void __launch_bounds__(256, 8) k_fused(const unsigned short* __restrict__ Yh,
                                                  const int* __restrict__ row_off,
                                                  const int2* __restrict__ csr_cv,
                                                  const float* __restrict__ G,
                                                  const float* __restrict__ Y0,
                                                  const unsigned short* __restrict__ Y0h,
                                                  unsigned short* __restrict__ Yhout,
                                                  float* __restrict__ stats,
                                                  int writeF, int n) {
    __shared__ float sSY[32 * MDIM];    // 16 KB (reused for BN partials at the end)
    int tid = threadIdx.x;
    int ty = tid >> 5;          // group 0..7
    int tx = tid & 31;          // lane-in-group, owns features tx*4..tx*4+3
    int rbase = blockIdx.x * 32;
    const char* yb = (const char*)Yh;
    int lbo = tx * 8;           // lane byte offset within a Yh row

    // ---- gather phase: group ty handles rows rbase + ty*4 .. +3
    for (int i = 0; i < 4; ++i) {
        int rloc = ty * 4 + i;
        int e0 = row_off[rbase + rloc];
        int e1 = row_off[rbase + rloc + 1];
        float4 a = make_float4(0.f, 0.f, 0.f, 0.f);
        int e = e0;
        for (; e + 8 <= e1; e += 8) {
            int2 p0 = ldnt(&csr_cv[e + 0]);
            int2 p1 = ldnt(&csr_cv[e + 1]);
            int2 p2 = ldnt(&csr_cv[e + 2]);
            int2 p3 = ldnt(&csr_cv[e + 3]);
            int2 p4 = ldnt(&csr_cv[e + 4]);
            int2 p5 = ldnt(&csr_cv[e + 5]);
            int2 p6 = ldnt(&csr_cv[e + 6]);
            int2 p7 = ldnt(&csr_cv[e + 7]);
            ushort4 h0 = *(const ushort4*)(yb + (size_t)(p0.x + lbo));
            ushort4 h1 = *(const ushort4*)(yb + (size_t)(p1.x + lbo));
            ushort4 h2 = *(const ushort4*)(yb + (size_t)(p2.x + lbo));
            ushort4 h3 = *(const ushort4*)(yb + (size_t)(p3.x + lbo));
            ushort4 h4 = *(const ushort4*)(yb + (size_t)(p4.x + lbo));
            ushort4 h5 = *(const ushort4*)(yb + (size_t)(p5.x + lbo));
            ushort4 h6 = *(const ushort4*)(yb + (size_t)(p6.x + lbo));
            ushort4 h7 = *(const ushort4*)(yb + (size_t)(p7.x + lbo));
            float v0 = __int_as_float(p0.y);
            float v1 = __int_as_float(p1.y);
            float v2 = __int_as_float(p2.y);
            float v3 = __int_as_float(p3.y);
            float v4 = __int_as_float(p4.y);
            float v5 = __int_as_float(p5.y);
            float v6 = __int_as_float(p6.y);
            float v7 = __int_as_float(p7.y);
            a.x = fmaf(v0, bf2f(h0.x), a.x);
            a.y = fmaf(v0, bf2f(h0.y), a.y);
            a.z = fmaf(v0, bf2f(h0.z), a.z);
            a.w = fmaf(v0, bf2f(h0.w), a.w);
            a.x = fmaf(v1, bf2f(h1.x), a.x);
            a.y = fmaf(v1, bf2f(h1.y), a.y);
            a.z = fmaf(v1, bf2f(h1.z), a.z);
            a.w = fmaf(v1, bf2f(h1.w), a.w);
            a.x = fmaf(v2, bf2f(h2.x), a.x);
            a.y = fmaf(v2, bf2f(h2.y), a.y);
            a.z = fmaf(v2, bf2f(h2.z), a.z);
            a.w = fmaf(v2, bf2f(h2.w), a.w);
            a.x = fmaf(v3, bf2f(h3.x), a.x);
            a.y = fmaf(v3, bf2f(h3.y), a.y);
            a.z = fmaf(v3, bf2f(h3.z), a.z);
            a.w = fmaf(v3, bf2f(h3.w), a.w);
            a.x = fmaf(v4, bf2f(h4.x), a.x);
            a.y = fmaf(v4, bf2f(h4.y), a.y);
            a.z = fmaf(v4, bf2f(h4.z), a.z);
            a.w = fmaf(v4, bf2f(h4.w), a.w);
            a.x = fmaf(v5, bf2f(h5.x), a.x);
            a.y = fmaf(v5, bf2f(h5.y), a.y);
            a.z = fmaf(v5, bf2f(h5.z), a.z);
            a.w = fmaf(v5, bf2f(h5.w), a.w);
            a.x = fmaf(v6, bf2f(h6.x), a.x);
            a.y = fmaf(v6, bf2f(h6.y), a.y);
            a.z = fmaf(v6, bf2f(h6.z), a.z);
            a.w = fmaf(v6, bf2f(h6.w), a.w);
            a.x = fmaf(v7, bf2f(h7.x), a.x);
            a.y = fmaf(v7, bf2f(h7.y), a.y);
            a.z = fmaf(v7, bf2f(h7.z), a.z);
            a.w = fmaf(v7, bf2f(h7.w), a.w);
        }
        for (; e + 4 <= e1; e += 4) {
            int2 p0 = ldnt(&csr_cv[e + 0]);
            int2 p1 = ldnt(&csr_cv[e + 1]);
            int2 p2 = ldnt(&csr_cv[e + 2]);
            int2 p3 = ldnt(&csr_cv[e + 3]);
            ushort4 h0 = *(const ushort4*)(yb + (size_t)(p0.x + lbo));
            ushort4 h1 = *(const ushort4*)(yb + (size_t)(p1.x + lbo));
            ushort4 h2 = *(const ushort4*)(yb + (size_t)(p2.x + lbo));
            ushort4 h3 = *(const ushort4*)(yb + (size_t)(p3.x + lbo));
            float v0 = __int_as_float(p0.y);
            float v1 = __int_as_float(p1.y);
            float v2 = __int_as_float(p2.y);
            float v3 = __int_as_float(p3.y);
            a.x = fmaf(v0, bf2f(h0.x), a.x);
            a.y = fmaf(v0, bf2f(h0.y), a.y);
            a.z = fmaf(v0, bf2f(h0.z), a.z);
            a.w = fmaf(v0, bf2f(h0.w), a.w);
            a.x = fmaf(v1, bf2f(h1.x), a.x);
            a.y = fmaf(v1, bf2f(h1.y), a.y);
            a.z = fmaf(v1, bf2f(h1.z), a.z);
            a.w = fmaf(v1, bf2f(h1.w), a.w);
            a.x = fmaf(v2, bf2f(h2.x), a.x);
            a.y = fmaf(v2, bf2f(h2.y), a.y);
            a.z = fmaf(v2, bf2f(h2.z), a.z);
            a.w = fmaf(v2, bf2f(h2.w), a.w);
            a.x = fmaf(v3, bf2f(h3.x), a.x);
            a.y = fmaf(v3, bf2f(h3.y), a.y);
            a.z = fmaf(v3, bf2f(h3.z), a.z);
            a.w = fmaf(v3, bf2f(h3.w), a.w);
        }
        for (; e < e1; ++e) {
            int2 p = ldnt(&csr_cv[e]);
            float v = __int_as_float(p.y);
            ushort4 h = *(const ushort4*)(yb + (size_t)(p.x + lbo));
            a.x = fmaf(v, bf2f(h.x), a.x);
            a.y = fmaf(v, bf2f(h.y), a.y);
            a.z = fmaf(v, bf2f(h.z), a.z);
            a.w = fmaf(v, bf2f(h.w), a.w);
        }
        // dense phase reads these rows only from the same wave64 ->
        // intra-wave ordering suffices, no block barrier needed.
        *(float4*)&sSY[rloc * MDIM + tx * 4] = a;
    }

    // ---- dense phase: thread computes 4 rows x 4 features, G from L1/L2
    size_t r0 = (size_t)rbase + ty * 4;
    int f0 = tx * 4;
    float4 acc[4];
    #pragma unroll
    for (int i = 0; i < 4; ++i) acc[i] = make_float4(0.f, 0.f, 0.f, 0.f);

    for (int j = 0; j < MDIM; j += 4) {
        float4 g0 = *(const float4*)&G[(j + 0) * MDIM + f0];
        float4 g1 = *(const float4*)&G[(j + 1) * MDIM + f0];
        float4 g2 = *(const float4*)&G[(j + 2) * MDIM + f0];
        float4 g3 = *(const float4*)&G[(j + 3) * MDIM + f0];
        #pragma unroll
        for (int i = 0; i < 4; ++i) {
            float4 sr = *(const float4*)&sSY[(ty * 4 + i) * MDIM + j];
            acc[i].x = fmaf(sr.x, g0.x, acc[i].x);
            acc[i].y = fmaf(sr.x, g0.y, acc[i].y);
            acc[i].z = fmaf(sr.x, g0.z, acc[i].z);
            acc[i].w = fmaf(sr.x, g0.w, acc[i].w);
            acc[i].x = fmaf(sr.y, g1.x, acc[i].x);
            acc[i].y = fmaf(sr.y, g1.y, acc[i].y);
            acc[i].z = fmaf(sr.y, g1.z, acc[i].z);
            acc[i].w = fmaf(sr.y, g1.w, acc[i].w);
            acc[i].x = fmaf(sr.z, g2.x, acc[i].x);
            acc[i].y = fmaf(sr.z, g2.y, acc[i].y);
            acc[i].z = fmaf(sr.z, g2.z, acc[i].z);
            acc[i].w = fmaf(sr.z, g2.w, acc[i].w);
            acc[i].x = fmaf(sr.w, g3.x, acc[i].x);
            acc[i].y = fmaf(sr.w, g3.y, acc[i].y);
            acc[i].z = fmaf(sr.w, g3.z, acc[i].z);
            acc[i].w = fmaf(sr.w, g3.w, acc[i].w);
        }
    }

    float4 bs = make_float4(0.f, 0.f, 0.f, 0.f);
    float4 bq = make_float4(0.f, 0.f, 0.f, 0.f);
    #pragma unroll
    for (int i = 0; i < 4; ++i) {
        float4 y0;
        if (writeF) {
            y0 = *(const float4*)&Y0[(r0 + i) * MDIM + f0];
        } else {
            ushort4 t4 = *(const ushort4*)&Y0h[(r0 + i) * MDIM + f0];
            y0.x = bf2f(t4.x);
            y0.y = bf2f(t4.y);
            y0.z = bf2f(t4.z);
            y0.w = bf2f(t4.w);
        }
        float4 o;
        o.x = acc[i].x + y0.x;
        o.y = acc[i].y + y0.y;
        o.z = acc[i].z + y0.z;
        o.w = acc[i].w + y0.w;
        if (writeF) {
            bs.x += o.x; bs.y += o.y; bs.z += o.z; bs.w += o.w;
            bq.x = fmaf(o.x, o.x, bq.x);
            bq.y = fmaf(o.y, o.y, bq.y);
            bq.z = fmaf(o.z, o.z, bq.z);
            bq.w = fmaf(o.w, o.w, bq.w);
        }
        ushort4 h;
        h.x = f2bf(o.x);
        h.y = f2bf(o.y);
        h.z = f2bf(o.z);
        h.w = f2bf(o.w);
        *(ushort4*)&Yhout[(r0 + i) * MDIM + f0] = h;
    }

    // ---- fused BN partial stats (final iteration only; exact fp32 o)
    if (writeF) {
        __syncthreads();  // everyone done reading sSY
        *(float4*)&sSY[ty * MDIM + f0] = bs;
        *(float4*)&sSY[8 * MDIM + ty * MDIM + f0] = bq;
        __syncthreads();
        if (tid < MDIM) {
            float a = 0.f, b = 0.f;
            #pragma unroll
            for (int t = 0; t < 8; ++t) {
                a += sSY[t * MDIM + tid];
                b += sSY[8 * MDIM + t * MDIM + tid];
            }
            atomicAdd(&stats[tid], a);
            atomicAdd(&stats[MDIM + tid], b);
        }
    }
}

// ---------------------------------------------------------------- BN finalize
__global__ void k_finalize(const float* __restrict__ stats, const float* __restrict__ B,
                           const float* __restrict__ bnw, const float* __restrict__ bnb,
                           float* __restrict__ Bs, float* __restrict__ cvec, int n) {
    int f = threadIdx.x;
    float inv_n = 1.f / (float)n;
    float mu = stats[f] * inv_n;
    float var = stats[MDIM + f] * inv_n - mu * mu;
    float rs = rsqrtf(var + 1e-5f);
    float sw = rs * bnw[f];
    float cv = bnb[f] - mu * sw;
    __shared__ float red[MDIM];
    for (int o = 0; o < MY; ++o) {
        float b = B[o * MDIM + f];
        Bs[o * MDIM + f] = b * sw;
        red[f] = b * cv;
        __syncthreads();
        for (int s = 64; s > 0; s >>= 1) {
            if (f < s) red[f] += red[f + s];
            __syncthreads();
        }
        if (f == 0) cvec[o] = red[0];
        __syncthreads();
    }
}

// ---------------------------------------------------------------- projection (bf16 input)
__global__ void __launch_bounds__(256) k_project(const unsigned short* __restrict__ Yh,
                                                 const float* __restrict__ Bs,
                                                 const float* __restrict__ cvec,
                                                 float* __restrict__ out, int n) {
    __shared__ float yt[16 * 129];
    __shared__ float sB[MY * 129];
    __shared__ float sc[MY];
    int tid = threadIdx.x;
    size_t rbase = (size_t)blockIdx.x * 16;
    for (int idx = tid; idx < 16 * MDIM / 4; idx += 256) {
        int r = idx >> 5;             // 32 ushort4 per row
        int f = (idx & 31) * 4;
        ushort4 h = *(const ushort4*)&Yh[(rbase + r) * MDIM + f];
        yt[r * 129 + f + 0] = bf2f(h.x);
        yt[r * 129 + f + 1] = bf2f(h.y);
        yt[r * 129 + f + 2] = bf2f(h.z);
        yt[r * 129 + f + 3] = bf2f(h.w);
    }
    for (int idx = tid; idx < MY * MDIM; idx += 256) {
        int o = idx >> 7, f = idx & 127;
        sB[o * 129 + f] = Bs[idx];
    }
    if (tid < MY) sc[tid] = cvec[tid];
    __syncthreads();
    if (tid < 16 * MY) {
        int r = tid / MY, o = tid % MY;
        float acc = sc[o];
        for (int f = 0; f < MDIM; ++f)
            acc = fmaf(yt[r * 129 + f], sB[o * 129 + f], acc);
        out[(rbase + r) * MY + o] = acc;
    }
}

// ---------------------------------------------------------------- launch
extern "C" void kernel_launch(void* const* d_in, const int* in_sizes, int n_in,
                              void* d_out, int out_size, void* d_ws, size_t ws_size,
                              hipStream_t stream) {
    const float* X    = (const float*)d_in[0];
    const float* F    = (const float*)d_in[1];
    const float* B    = (const float*)d_in[2];
    const float* bnw  = (const float*)d_in[3];
    const float* bnb  = (const float*)d_in[4];
    const float* ev   = (const float*)d_in[5];
    const int*   erow = (const int*)d_in[6];
    const int*   ecol = (const int*)d_in[7];
    float* out = (float*)d_out;
    const int n = in_sizes[0] / MDIM;  // 100000
    const int E = in_sizes[5];         // 1600000

    char* w = (char*)d_ws;
    size_t off = 0;
    auto carve = [&](size_t bytes) -> void* {
        void* p = w + off;
        off += (bytes + 255) & ~(size_t)255;
        return p;
    };
    float*          Y0    = (float*)carve((size_t)n * MDIM * 4);
    unsigned short* Y0h   = (unsigned short*)carve((size_t)n * MDIM * 2);  // bf16 anchor
    unsigned short* Yh_a  = (unsigned short*)carve((size_t)n * MDIM * 2);  // bf16 state ping
    unsigned short* Yh_b  = (unsigned short*)carve((size_t)n * MDIM * 2);  // bf16 state pong
    float* FF        = (float*)carve(MDIM * MDIM * 4);
    float* G         = (float*)carve(MDIM * MDIM * 4);
    int2*  csr_cv    = (int2*)carve((size_t)E * 8);
    int*   row_off   = (int*)carve((size_t)(n + 1) * 4);
    int*   cursor    = (int*)carve((size_t)n * 4);
    int*   cnt       = (int*)carve((size_t)n * 4);
    int*   blockSums = (int*)carve(1024 * 4);
    float* normAcc   = (float*)carve(4);
    float* stats     = (float*)carve(2 * MDIM * 4);
    float* Bs        = (float*)carve(MY * MDIM * 4);
    float* cvec      = (float*)carve(MY * 4);
    (void)ws_size;

    hipMemsetAsync(cnt, 0, (size_t)n * 4, stream);
    hipMemsetAsync(normAcc, 0, 4, stream);
    hipMemsetAsync(stats, 0, 2 * MDIM * 4, stream);

    k_transpose<<<dim3(n / 32, MDIM / 32), dim3(32, 8), 0, stream>>>(X, Y0, Y0h, Yh_a, n);
    k_gram<<<MDIM, MDIM, 0, stream>>>(F, FF, normAcc);
    k_gnorm<<<MDIM * MDIM / 256, 256, 0, stream>>>(FF, normAcc, G);

    const int nb = (n + 1023) / 1024;
    k_hist<<<(E + 255) / 256, 256, 0, stream>>>(erow, cnt, E);
    k_scan1<<<nb, 256, 0, stream>>>(cnt, blockSums, n);
    k_scan2<<<1, 256, 0, stream>>>(blockSums, row_off, nb, n);
    k_scan3<<<nb, 256, 0, stream>>>(cnt, blockSums, row_off, cursor, n);
    k_scatter<<<(E + 255) / 256, 256, 0, stream>>>(erow, ecol, ev, cursor, csr_cv, E);

    for (int k = 0; k < KITER; ++k) {
        const unsigned short* hin = (k & 1) ? Yh_b : Yh_a;
        unsigned short*       hout = (k & 1) ? Yh_a : Yh_b;
        int writeF = (k == KITER - 1) ? 1 : 0;
        k_fused<<<(n + 31) / 32, 256, 0, stream>>>(hin, row_off, csr_cv, G, Y0, Y0h,
                                                   hout, stats, writeF, n);
    }

    const unsigned short* Yfinal = (KITER & 1) ? Yh_b : Yh_a;
    k_finalize<<<1, MDIM, 0, stream>>>(stats, B, bnw, bnb, Bs, cvec, n);
    k_project<<<n / 16, 256, 0, stream>>>(Yfinal, Bs, cvec, out, n);
}